// Round 5
// baseline (166.784 us; speedup 1.0000x reference)
//
#include <hip/hip_runtime.h>

#define DEVI static __device__ __forceinline__

typedef unsigned short u16;
typedef unsigned int u32;
typedef __attribute__((ext_vector_type(8))) __bf16 bf16x8;
typedef __attribute__((ext_vector_type(8))) short short8;
typedef __attribute__((ext_vector_type(4))) float f32x4;

DEVI u16 f2bf(float f) {
  union { float f; u32 u; } v; v.f = f;
  u32 r = v.u + 0x7fffu + ((v.u >> 16) & 1u);  // RNE
  return (u16)(r >> 16);
}

DEVI u16 bfc(float f) {
  union { __bf16 b; u16 u; } v; v.b = (__bf16)f; return v.u;
}

DEVI void gload16(const void* g, void* l) {
  __builtin_amdgcn_global_load_lds(
      (const __attribute__((address_space(1))) void*)g,
      (__attribute__((address_space(3))) void*)l,
      16, 0, 0);
}

// ---------------- fp32 -> bf16 convert (vectorized) ----------------
__global__ void k_cvt(const float* __restrict__ in, u16* __restrict__ out, int n4) {
  int i = blockIdx.x * blockDim.x + threadIdx.x;
  if (i >= n4) return;
  const float4 v = reinterpret_cast<const float4*>(in)[i];
  ushort4 o;
  o.x = f2bf(v.x); o.y = f2bf(v.y); o.z = f2bf(v.z); o.w = f2bf(v.w);
  reinterpret_cast<ushort4*>(out)[i] = o;
}

// ---------------- mask -> additive float bias ----------------
__global__ void k_maskbias(const int* __restrict__ m, float* __restrict__ bias, int n) {
  int i = blockIdx.x * blockDim.x + threadIdx.x;
  if (i < n) bias[i] = (m[i] == 1) ? 0.f : -1e30f;
}

// ---------------- W[k][n] fp32 -> Wt[n][k] bf16 (1024x1024) ----------------
__global__ void k_transcvt(const float* __restrict__ W, u16* __restrict__ Wt) {
  __shared__ float tl[32][33];
  const int n0 = blockIdx.x * 32, k0 = blockIdx.y * 32;
  const int tx = threadIdx.x, ty = threadIdx.y;
#pragma unroll
  for (int r = ty; r < 32; r += 8)
    tl[r][tx] = W[(size_t)(k0 + r) * 1024 + n0 + tx];
  __syncthreads();
#pragma unroll
  for (int r = ty; r < 32; r += 8)
    Wt[(size_t)(n0 + r) * 1024 + k0 + tx] = f2bf(tl[tx][r]);
}

// ---------------- GEMM: C[M][N] = (A[M][K](bf16) * Bt[N][K](bf16) + bias) * scale ----
DEVI void store1(u16* C, size_t i, float v) { C[i] = f2bf(v); }
DEVI void store1(float* C, size_t i, float v) { C[i] = v; }

template <typename OutT>
__global__ __launch_bounds__(256, 2) void k_gemm_bt(
    const u16* __restrict__ Abase, long aZ,
    const u16* __restrict__ Btbase, long bZ,
    const float* __restrict__ bias0, const float* __restrict__ bias1,
    const float* __restrict__ bias2,
    float s0, float s1, float s2,
    OutT* __restrict__ Cbase, long cZ, u16* __restrict__ Vt,
    int M, int N, int K) {
  const int z = blockIdx.z;
  const u16* A  = Abase  + (size_t)z * aZ;
  const u16* Bt = Btbase + (size_t)z * bZ;
  OutT* C = Cbase + (size_t)z * cZ;
  const float* bias = (z == 0) ? bias0 : ((z == 1) ? bias1 : bias2);
  const float scl = (z == 0) ? s0 : ((z == 1) ? s1 : s2);

  __shared__ u16 lsA[128 * 32];
  __shared__ u16 lsB[128 * 32];

  const int t = threadIdx.x;
  const int w = t >> 6, ln = t & 63;
  const int l15 = ln & 15, lhi = ln >> 4;
  const int wr = w >> 1, wc = w & 1;
  const int m0 = blockIdx.x * 128, n0 = blockIdx.y * 128;

  f32x4 acc[4][4] = {};

  for (int kt = 0; kt < K; kt += 32) {
#pragma unroll
    for (int i = 0; i < 2; ++i) {
      const int li = i * 256 + t;
      const int row = li >> 2, cb = (li & 3) << 3;
      gload16(A + (size_t)(m0 + row) * K + kt + cb,
              (char*)lsA + (i * 256 + w * 64) * 16);
      gload16(Bt + (size_t)(n0 + row) * K + kt + cb,
              (char*)lsB + (i * 256 + w * 64) * 16);
    }
    __syncthreads();

    bf16x8 af[4], bf_[4];
#pragma unroll
    for (int m = 0; m < 4; ++m)
      af[m] = *reinterpret_cast<const bf16x8*>(
          &lsA[(wr * 64 + m * 16 + l15) * 32 + lhi * 8]);
#pragma unroll
    for (int n = 0; n < 4; ++n)
      bf_[n] = *reinterpret_cast<const bf16x8*>(
          &lsB[(wc * 64 + n * 16 + l15) * 32 + lhi * 8]);
#pragma unroll
    for (int m = 0; m < 4; ++m)
#pragma unroll
      for (int n = 0; n < 4; ++n)
        acc[m][n] = __builtin_amdgcn_mfma_f32_16x16x32_bf16(af[m], bf_[n], acc[m][n], 0, 0, 0);
    __syncthreads();
  }

  if (Vt != nullptr && z == 2) {
    // transposed write: Vt[(b*1024 + c)][s], 4 consecutive tokens per quad
#pragma unroll
    for (int n = 0; n < 4; ++n) {
      const int c = n0 + wc * 64 + n * 16 + l15;
      const float bv = bias[c];
#pragma unroll
      for (int m = 0; m < 4; ++m) {
        const int r = m0 + wr * 64 + m * 16 + lhi * 4;
        ushort4 s4;
#pragma unroll
        for (int j = 0; j < 4; ++j) ((u16*)&s4)[j] = f2bf(acc[m][n][j] + bv);
        *reinterpret_cast<ushort4*>(
            &Vt[((size_t)((r >> 11) * 1024 + c)) * 2048 + (r & 2047)]) = s4;
      }
    }
    return;
  }

#pragma unroll
  for (int n = 0; n < 4; ++n) {
    const int c = n0 + wc * 64 + n * 16 + l15;
    const float bv = bias[c];
#pragma unroll
    for (int m = 0; m < 4; ++m)
#pragma unroll
      for (int j = 0; j < 4; ++j) {
        const int r = m0 + wr * 64 + m * 16 + lhi * 4 + j;
        store1(C, (size_t)r * N + c, (acc[m][n][j] + bv) * scl);
      }
  }
}

// ---------------- flash attention ----------------
// flat grid 1024, XCD-grouped: each XCD owns 4 (b,h) pairs x 32 qt blocks
// (per-XCD hot K/Vt = 2MB < 4MB L2). 256 threads = 4 waves, 16 q-rows/wave.
// Single-buffered K/V LDS (27.6KB total -> 4 blocks/CU = 4 waves/SIMD) with
// early-issue staging: next tile's global loads issued before compute, LDS
// write after barrier (vmcnt covered by compute). T13 defer-max rescale.
// Q pre-scaled by 0.125*log2(e). K row-major [B*S][H]; Vt transposed [B*H][S].
__global__ __launch_bounds__(256) void k_attn(
    const u16* __restrict__ Q, const u16* __restrict__ K, const u16* __restrict__ Vt,
    const float* __restrict__ MB, u16* __restrict__ O) {
  __shared__ u16 lsK[64][72];      // [key][d]   pad-72: conflict-minimal b128
  __shared__ u16 lsV[64][72];      // [d][key]
  __shared__ u16 lsPt[4][16][72];  // per-wave P[q_local][key] bf16

  const int t = threadIdx.x, w = t >> 6, ln = t & 63;
  const int l15 = ln & 15, lhi = ln >> 4;
  // XCD-grouped block mapping (bijection; perf-only heuristic)
  const int fid = blockIdx.x;              // 0..1023
  const int xcd = fid & 7, slot = fid >> 3;  // slot 0..127
  const int pair = xcd * 4 + (slot >> 5);    // 0..31
  const int qt = slot & 31;                  // 0..31
  const int h = pair & 15, b = pair >> 4;

  const size_t rowQ = (size_t)b * 2048 + qt * 64 + w * 16;
  const int hc = h * 64;

  // staging geometry: thread covers row=t>>3 (0..31) and row+32, col8=(t&7)*8
  const int srow = t >> 3, scol = (t & 7) << 3;
  const u16* Kg = K + ((size_t)b * 2048 + srow) * 1024 + hc + scol;       // +nt*1024
  const u16* Vg = Vt + ((size_t)(b * 1024 + hc) + srow) * 2048 + scol;    // +nt

  // Q fragments (B-operand): row q = l15, k-cols = ks*32+lhi*8
  bf16x8 qb[2];
#pragma unroll
  for (int ks = 0; ks < 2; ++ks)
    qb[ks] = *reinterpret_cast<const bf16x8*>(
        &Q[(rowQ + l15) * 1024 + hc + ks * 32 + lhi * 8]);

  f32x4 o[4] = {};  // O^T[d-frag nd], col q = l15
  float mrow = -1e30f, lsum = 0.f;

  // prologue: stage tile 0
  short8 rk0, rk1, rv0, rv1;
  rk0 = *reinterpret_cast<const short8*>(Kg);
  rk1 = *reinterpret_cast<const short8*>(Kg + 32 * 1024);
  rv0 = *reinterpret_cast<const short8*>(Vg);
  rv1 = *reinterpret_cast<const short8*>(Vg + 32 * 2048);
  *reinterpret_cast<short8*>(&lsK[srow][scol]) = rk0;
  *reinterpret_cast<short8*>(&lsK[32 + srow][scol]) = rk1;
  *reinterpret_cast<short8*>(&lsV[srow][scol]) = rv0;
  *reinterpret_cast<short8*>(&lsV[32 + srow][scol]) = rv1;
  __syncthreads();

  for (int nt = 0; nt < 2048; nt += 64) {
    // issue next tile's global loads early (latency hides under compute)
    const int ntn = (nt + 64 < 2048) ? nt + 64 : 0;
    rk0 = *reinterpret_cast<const short8*>(Kg + (size_t)ntn * 1024);
    rk1 = *reinterpret_cast<const short8*>(Kg + (size_t)(ntn + 32) * 1024);
    rv0 = *reinterpret_cast<const short8*>(Vg + ntn);
    rv1 = *reinterpret_cast<const short8*>(Vg + 32 * 2048 + ntn);

    // S^T = K Q^T : st[nk], row = key = nk*16+lhi*4+j, col = q = l15
    f32x4 st[4] = {};
    __builtin_amdgcn_s_setprio(1);
#pragma unroll
    for (int nk = 0; nk < 4; ++nk)
#pragma unroll
      for (int ks = 0; ks < 2; ++ks) {
        const bf16x8 kb = *reinterpret_cast<const bf16x8*>(
            &lsK[nk * 16 + l15][ks * 32 + lhi * 8]);
        st[nk] = __builtin_amdgcn_mfma_f32_16x16x32_bf16(kb, qb[ks], st[nk], 0, 0, 0);
      }
    __builtin_amdgcn_s_setprio(0);

    // additive key-padding bias
#pragma unroll
    for (int nk = 0; nk < 4; ++nk) {
      const f32x4 bv = *reinterpret_cast<const f32x4*>(&MB[b * 2048 + nt + nk * 16 + lhi * 4]);
#pragma unroll
      for (int j = 0; j < 4; ++j) st[nk][j] += bv[j];
    }

    // online softmax: lane's column q = l15; 16 in-reg + xor16/xor32
    float tm = st[0][0];
#pragma unroll
    for (int nk = 0; nk < 4; ++nk)
#pragma unroll
      for (int j = 0; j < 4; ++j) tm = fmaxf(tm, st[nk][j]);
    tm = fmaxf(tm, __shfl_xor(tm, 16, 64));
    tm = fmaxf(tm, __shfl_xor(tm, 32, 64));

    // T13 defer-max: only rescale when max grew by > 8 (exp2 units; P <= 2^8)
    const bool trig = tm > mrow + 8.f;
    if (__any(trig)) {
      const float al = trig ? __builtin_amdgcn_exp2f(mrow - tm) : 1.f;
      if (trig) mrow = tm;
      lsum *= al;
#pragma unroll
      for (int nd = 0; nd < 4; ++nd)
#pragma unroll
        for (int j = 0; j < 4; ++j) o[nd][j] *= al;
    }

    float rs = 0.f;
#pragma unroll
    for (int nk = 0; nk < 4; ++nk)
#pragma unroll
      for (int j = 0; j < 4; ++j) {
        const float p = __builtin_amdgcn_exp2f(st[nk][j] - mrow);
        st[nk][j] = p;
        rs += p;
      }
    rs += __shfl_xor(rs, 16, 64);
    rs += __shfl_xor(rs, 32, 64);
    lsum += rs;

    // P -> LDS (bf16, b64 writes; per-wave buffer, in-order DS pipe)
#pragma unroll
    for (int nk = 0; nk < 4; ++nk) {
      ushort4 pk;
      pk.x = bfc(st[nk][0]); pk.y = bfc(st[nk][1]);
      pk.z = bfc(st[nk][2]); pk.w = bfc(st[nk][3]);
      *reinterpret_cast<ushort4*>(&lsPt[w][l15][nk * 16 + lhi * 4]) = pk;
    }

    // O^T += V^T P^T
    __builtin_amdgcn_s_setprio(1);
#pragma unroll
    for (int ks = 0; ks < 2; ++ks) {
      const bf16x8 pb = *reinterpret_cast<const bf16x8*>(
          &lsPt[w][l15][ks * 32 + lhi * 8]);
#pragma unroll
      for (int nd = 0; nd < 4; ++nd) {
        const bf16x8 vt = *reinterpret_cast<const bf16x8*>(
            &lsV[nd * 16 + l15][ks * 32 + lhi * 8]);
        o[nd] = __builtin_amdgcn_mfma_f32_16x16x32_bf16(vt, pb, o[nd], 0, 0, 0);
      }
    }
    __builtin_amdgcn_s_setprio(0);

    // single-buffer swap: all waves done reading, then write next tile
    __syncthreads();
    *reinterpret_cast<short8*>(&lsK[srow][scol]) = rk0;
    *reinterpret_cast<short8*>(&lsK[32 + srow][scol]) = rk1;
    *reinterpret_cast<short8*>(&lsV[srow][scol]) = rv0;
    *reinterpret_cast<short8*>(&lsV[32 + srow][scol]) = rv1;
    __syncthreads();
  }

  // epilogue: O[q][d], q = l15, d = nd*16+lhi*4+j
  const float inv = 1.f / lsum;
#pragma unroll
  for (int nd = 0; nd < 4; ++nd) {
    ushort4 s4;
    s4.x = bfc(o[nd][0] * inv); s4.y = bfc(o[nd][1] * inv);
    s4.z = bfc(o[nd][2] * inv); s4.w = bfc(o[nd][3] * inv);
    *reinterpret_cast<ushort4*>(
        &O[(rowQ + l15) * 1024 + hc + nd * 16 + lhi * 4]) = s4;
  }
}

extern "C" void kernel_launch(void* const* d_in, const int* in_sizes, int n_in,
                              void* d_out, int out_size, void* d_ws, size_t ws_size,
                              hipStream_t stream) {
  const float* x_q = (const float*)d_in[0];
  const float* x_k = (const float*)d_in[1];
  const float* x_v = (const float*)d_in[2];
  const int*   msk = (const int*)d_in[3];
  const float* Wq  = (const float*)d_in[4];
  const float* bq  = (const float*)d_in[5];
  const float* Wk  = (const float*)d_in[6];
  const float* bk  = (const float*)d_in[7];
  const float* Wv  = (const float*)d_in[8];
  const float* bv  = (const float*)d_in[9];
  const float* Wo  = (const float*)d_in[10];
  const float* bo  = (const float*)d_in[11];

  const size_t NTOK = 4096, H = 1024;
  u16* xbf  = (u16*)d_ws;            // 3 * 4096*1024 bf16
  u16* wt   = xbf + 3 * NTOK * H;    // 4 * 1024*1024 bf16 (transposed weights)
  u16* qkv  = wt  + 4 * H * H;       // Q,K row-major; V slot holds Vt (transposed)
  u16* aout = qkv + 3 * NTOK * H;    // 4096*1024 bf16
  float* mb = (float*)(aout + NTOK * H);  // 4096 floats
  u16* vtb  = qkv + 2 * NTOK * H;    // Vt[b*1024 + c][s] (reuses V slot)

  k_cvt<<<dim3(4096), dim3(256), 0, stream>>>(x_q, xbf,              1048576);
  k_cvt<<<dim3(4096), dim3(256), 0, stream>>>(x_k, xbf + NTOK * H,   1048576);
  k_cvt<<<dim3(4096), dim3(256), 0, stream>>>(x_v, xbf + 2 * NTOK * H, 1048576);
  k_maskbias<<<dim3(16), dim3(256), 0, stream>>>(msk, mb, 4096);
  k_transcvt<<<dim3(32, 32), dim3(32, 8), 0, stream>>>(Wq, wt);
  k_transcvt<<<dim3(32, 32), dim3(32, 8), 0, stream>>>(Wk, wt + H * H);
  k_transcvt<<<dim3(32, 32), dim3(32, 8), 0, stream>>>(Wv, wt + 2 * H * H);
  k_transcvt<<<dim3(32, 32), dim3(32, 8), 0, stream>>>(Wo, wt + 3 * H * H);

  // Q,K,V = x{q,k,v} @ W{q,k,v} + b{q,k,v}; Q scaled by 0.125*log2(e) for exp2 softmax
  // z==2 (V) writes transposed into vtb.
  const float qscale = 0.125f * 1.4426950408889634f;
  k_gemm_bt<u16><<<dim3(32, 8, 3), dim3(256), 0, stream>>>(
      xbf, (long)(NTOK * H), wt, (long)(H * H), bq, bk, bv,
      qscale, 1.f, 1.f,
      qkv, (long)(NTOK * H), vtb, 4096, 1024, 1024);

  // attention (flat grid, XCD-grouped mapping inside)
  k_attn<<<dim3(1024), dim3(256), 0, stream>>>(
      qkv, qkv + NTOK * H, vtb, mb, aout);

  // out = attn_out @ Wo + bo  (fp32 output)
  k_gemm_bt<float><<<dim3(32, 8, 1), dim3(256), 0, stream>>>(
      aout, 0L, wt + 3 * H * H, 0L, bo, bo, bo,
      1.f, 1.f, 1.f,
      (float*)d_out, 0L, nullptr, 4096, 1024, 1024);
}

// Round 7
// 159.467 us; speedup vs baseline: 1.0459x; 1.0459x over previous
//
#include <hip/hip_runtime.h>

#define DEVI static __device__ __forceinline__

typedef unsigned short u16;
typedef unsigned int u32;
typedef __attribute__((ext_vector_type(8))) __bf16 bf16x8;
typedef __attribute__((ext_vector_type(8))) short short8;
typedef __attribute__((ext_vector_type(4))) float f32x4;
typedef __attribute__((ext_vector_type(16))) float f32x16;
typedef __attribute__((ext_vector_type(4))) u32 u32x4;

DEVI u16 f2bf(float f) {
  union { float f; u32 u; } v; v.f = f;
  u32 r = v.u + 0x7fffu + ((v.u >> 16) & 1u);  // RNE
  return (u16)(r >> 16);
}

DEVI u16 bfc(float f) {
  union { __bf16 b; u16 u; } v; v.b = (__bf16)f; return v.u;
}

DEVI void gload16(const void* g, void* l) {
  __builtin_amdgcn_global_load_lds(
      (const __attribute__((address_space(1))) void*)g,
      (__attribute__((address_space(3))) void*)l,
      16, 0, 0);
}

// ---------------- fp32 -> bf16 convert (vectorized) ----------------
__global__ void k_cvt(const float* __restrict__ in, u16* __restrict__ out, int n4) {
  int i = blockIdx.x * blockDim.x + threadIdx.x;
  if (i >= n4) return;
  const float4 v = reinterpret_cast<const float4*>(in)[i];
  ushort4 o;
  o.x = f2bf(v.x); o.y = f2bf(v.y); o.z = f2bf(v.z); o.w = f2bf(v.w);
  reinterpret_cast<ushort4*>(out)[i] = o;
}

// ---------------- mask -> additive float bias ----------------
__global__ void k_maskbias(const int* __restrict__ m, float* __restrict__ bias, int n) {
  int i = blockIdx.x * blockDim.x + threadIdx.x;
  if (i < n) bias[i] = (m[i] == 1) ? 0.f : -1e30f;
}

// ---------------- W[k][n] fp32 -> Wt[n][k] bf16 (1024x1024) ----------------
__global__ void k_transcvt(const float* __restrict__ W, u16* __restrict__ Wt) {
  __shared__ float tl[32][33];
  const int n0 = blockIdx.x * 32, k0 = blockIdx.y * 32;
  const int tx = threadIdx.x, ty = threadIdx.y;
#pragma unroll
  for (int r = ty; r < 32; r += 8)
    tl[r][tx] = W[(size_t)(k0 + r) * 1024 + n0 + tx];
  __syncthreads();
#pragma unroll
  for (int r = ty; r < 32; r += 8)
    Wt[(size_t)(n0 + r) * 1024 + k0 + tx] = f2bf(tl[tx][r]);
}

// ---------------- GEMM: C[M][N] = (A[M][K](bf16) * Bt[N][K](bf16) + bias) * scale ----
DEVI void store1(u16* C, size_t i, float v) { C[i] = f2bf(v); }
DEVI void store1(float* C, size_t i, float v) { C[i] = v; }

template <typename OutT>
__global__ __launch_bounds__(256, 2) void k_gemm_bt(
    const u16* __restrict__ Abase, long aZ,
    const u16* __restrict__ Btbase, long bZ,
    const float* __restrict__ bias0, const float* __restrict__ bias1,
    const float* __restrict__ bias2,
    float s0, float s1, float s2,
    OutT* __restrict__ Cbase, long cZ, u16* __restrict__ Vt,
    int M, int N, int K) {
  const int z = blockIdx.z;
  const u16* A  = Abase  + (size_t)z * aZ;
  const u16* Bt = Btbase + (size_t)z * bZ;
  OutT* C = Cbase + (size_t)z * cZ;
  const float* bias = (z == 0) ? bias0 : ((z == 1) ? bias1 : bias2);
  const float scl = (z == 0) ? s0 : ((z == 1) ? s1 : s2);

  __shared__ u16 lsA[128 * 32];
  __shared__ u16 lsB[128 * 32];

  const int t = threadIdx.x;
  const int w = t >> 6, ln = t & 63;
  const int l15 = ln & 15, lhi = ln >> 4;
  const int wr = w >> 1, wc = w & 1;
  const int m0 = blockIdx.x * 128, n0 = blockIdx.y * 128;

  f32x4 acc[4][4] = {};

  for (int kt = 0; kt < K; kt += 32) {
#pragma unroll
    for (int i = 0; i < 2; ++i) {
      const int li = i * 256 + t;
      const int row = li >> 2, cb = (li & 3) << 3;
      gload16(A + (size_t)(m0 + row) * K + kt + cb,
              (char*)lsA + (i * 256 + w * 64) * 16);
      gload16(Bt + (size_t)(n0 + row) * K + kt + cb,
              (char*)lsB + (i * 256 + w * 64) * 16);
    }
    __syncthreads();

    bf16x8 af[4], bf_[4];
#pragma unroll
    for (int m = 0; m < 4; ++m)
      af[m] = *reinterpret_cast<const bf16x8*>(
          &lsA[(wr * 64 + m * 16 + l15) * 32 + lhi * 8]);
#pragma unroll
    for (int n = 0; n < 4; ++n)
      bf_[n] = *reinterpret_cast<const bf16x8*>(
          &lsB[(wc * 64 + n * 16 + l15) * 32 + lhi * 8]);
#pragma unroll
    for (int m = 0; m < 4; ++m)
#pragma unroll
      for (int n = 0; n < 4; ++n)
        acc[m][n] = __builtin_amdgcn_mfma_f32_16x16x32_bf16(af[m], bf_[n], acc[m][n], 0, 0, 0);
    __syncthreads();
  }

  if (Vt != nullptr && z == 2) {
    // transposed write: Vt[(b*1024 + c)][s], 4 consecutive tokens per quad
#pragma unroll
    for (int n = 0; n < 4; ++n) {
      const int c = n0 + wc * 64 + n * 16 + l15;
      const float bv = bias[c];
#pragma unroll
      for (int m = 0; m < 4; ++m) {
        const int r = m0 + wr * 64 + m * 16 + lhi * 4;
        ushort4 s4;
#pragma unroll
        for (int j = 0; j < 4; ++j) ((u16*)&s4)[j] = f2bf(acc[m][n][j] + bv);
        *reinterpret_cast<ushort4*>(
            &Vt[((size_t)((r >> 11) * 1024 + c)) * 2048 + (r & 2047)]) = s4;
      }
    }
    return;
  }

#pragma unroll
  for (int n = 0; n < 4; ++n) {
    const int c = n0 + wc * 64 + n * 16 + l15;
    const float bv = bias[c];
#pragma unroll
    for (int m = 0; m < 4; ++m)
#pragma unroll
      for (int j = 0; j < 4; ++j) {
        const int r = m0 + wr * 64 + m * 16 + lhi * 4 + j;
        store1(C, (size_t)r * N + c, (acc[m][n][j] + bv) * scl);
      }
  }
}

// ---------------- flash attention (32x32 MFMA, in-lane P) ----------------
// grid 512 flat, XCD-grouped. 256 threads = 4 waves, 32 q-rows/wave (q=lane&31).
// KVBLK=64, double-buffered K/V LDS, reg-staged, ONE barrier/tile.
// P never leaves registers: lsV's key axis is stored with key-bits 2<->3
// swapped (sigma), which makes the PV B-operand exactly C/D regs 8s..8s+7 of
// st[f] per 16-key slice -- no cross-lane ops, no P LDS. Cross-half softmax
// reduce = __shfl_xor(32). T13 defer-max.
// Q pre-scaled by 0.125*log2(e). K row-major [B*S][H]; Vt transposed [B*H][S].
__global__ __launch_bounds__(256, 2) void k_attn(
    const u16* __restrict__ Q, const u16* __restrict__ K, const u16* __restrict__ Vt,
    const float* __restrict__ MB, u16* __restrict__ O) {
  __shared__ u16 lsK[2][64][72];  // [buf][key][d]
  __shared__ u16 lsV[2][64][72];  // [buf][d][key']  key' = sigma(key)

  const int t = threadIdx.x, w = t >> 6, ln = t & 63;
  const int l31 = ln & 31, h = ln >> 5, h8 = h * 8;
  // XCD-grouped block mapping (bijection)
  const int fid = blockIdx.x;                // 0..511
  const int xcd = fid & 7, slot = fid >> 3;  // 0..63
  const int pair = xcd * 4 + (slot >> 4);    // 0..31
  const int qt = slot & 15;
  const int hh = pair & 15, b = pair >> 4;

  const size_t rowQ = (size_t)b * 2048 + qt * 128 + w * 32;
  const int hc = hh * 64;

  // staging geometry: thread covers rows srow, srow+32; key chunk scol..scol+7
  const int srow = t >> 3, scol = (t & 7) << 3;
  const u16* Kg = K + ((size_t)b * 2048 + srow) * 1024 + hc + scol;  // +nt*1024
  // V: sigma staging -- thread's key' chunk [scol,scol+8) comes from global
  // keys {g16+4*half+0..3, g16+8+4*half+0..3}, g16=16-group, half=(scol>>3)&1
  const int half = t & 1;
  const int g16 = ((t & 7) >> 1) << 4;
  const u16* VgA = Vt + ((size_t)(b * 1024 + hc) + srow) * 2048 + g16 + 4 * half;
  const float* MBb = MB + b * 2048;

  // Q fragments (B-operand): col q = l31, k = d = ks*16 + h8 + e
  bf16x8 qb[4];
#pragma unroll
  for (int ks = 0; ks < 4; ++ks)
    qb[ks] = *reinterpret_cast<const bf16x8*>(
        &Q[(rowQ + l31) * 1024 + hc + ks * 16 + h8]);

  f32x16 o[2] = {};  // O^T[d-frag df2], col q = l31
  float mrow = -1e30f, lsum = 0.f;

  // prologue: stage tile 0 into buf 0
  short8 rk0, rk1;
  ushort4 rv0a, rv0b, rv1a, rv1b;
  rk0 = *reinterpret_cast<const short8*>(Kg);
  rk1 = *reinterpret_cast<const short8*>(Kg + 32 * 1024);
  rv0a = *reinterpret_cast<const ushort4*>(VgA);
  rv0b = *reinterpret_cast<const ushort4*>(VgA + 8);
  rv1a = *reinterpret_cast<const ushort4*>(VgA + 32 * 2048);
  rv1b = *reinterpret_cast<const ushort4*>(VgA + 32 * 2048 + 8);
  *reinterpret_cast<short8*>(&lsK[0][srow][scol]) = rk0;
  *reinterpret_cast<short8*>(&lsK[0][32 + srow][scol]) = rk1;
  *reinterpret_cast<ushort4*>(&lsV[0][srow][scol]) = rv0a;
  *reinterpret_cast<ushort4*>(&lsV[0][srow][scol + 4]) = rv0b;
  *reinterpret_cast<ushort4*>(&lsV[0][32 + srow][scol]) = rv1a;
  *reinterpret_cast<ushort4*>(&lsV[0][32 + srow][scol + 4]) = rv1b;
  __syncthreads();

  int cur = 0;
  for (int nt = 0; nt < 2048; nt += 64) {
    // issue next tile's global loads early (latency hides under compute)
    const int ntn = (nt + 64 < 2048) ? nt + 64 : 0;
    rk0 = *reinterpret_cast<const short8*>(Kg + (size_t)ntn * 1024);
    rk1 = *reinterpret_cast<const short8*>(Kg + (size_t)(ntn + 32) * 1024);
    rv0a = *reinterpret_cast<const ushort4*>(VgA + ntn);
    rv0b = *reinterpret_cast<const ushort4*>(VgA + ntn + 8);
    rv1a = *reinterpret_cast<const ushort4*>(VgA + 32 * 2048 + ntn);
    rv1b = *reinterpret_cast<const ushort4*>(VgA + 32 * 2048 + ntn + 8);

    // S^T = K Q^T : st[kf2], row = key = 32*kf2 + (r&3)+8*(r>>2)+4h, col = q = l31
    f32x16 st[2] = {};
    __builtin_amdgcn_s_setprio(1);
#pragma unroll
    for (int kf2 = 0; kf2 < 2; ++kf2)
#pragma unroll
      for (int ks = 0; ks < 4; ++ks) {
        const bf16x8 kb = *reinterpret_cast<const bf16x8*>(
            &lsK[cur][kf2 * 32 + l31][ks * 16 + h8]);
        st[kf2] = __builtin_amdgcn_mfma_f32_32x32x16_bf16(kb, qb[ks], st[kf2], 0, 0, 0);
      }
    __builtin_amdgcn_s_setprio(0);

    // additive key-padding bias: reg r -> key = 32f + 8*(r>>2) + 4h + (r&3)
#pragma unroll
    for (int f = 0; f < 2; ++f)
#pragma unroll
      for (int rg = 0; rg < 4; ++rg) {
        const f32x4 bv = *reinterpret_cast<const f32x4*>(
            &MBb[nt + f * 32 + rg * 8 + h * 4]);
#pragma unroll
        for (int jj = 0; jj < 4; ++jj) st[f][rg * 4 + jj] += bv[jj];
      }

    // online softmax: lane holds 32 of 64 keys for its q; cross = lane^32
    float tm = st[0][0];
#pragma unroll
    for (int f = 0; f < 2; ++f)
#pragma unroll
      for (int i = 0; i < 16; ++i) tm = fmaxf(tm, st[f][i]);
    tm = fmaxf(tm, __shfl_xor(tm, 32, 64));

    // T13 defer-max: rescale only when max grew > 8 (exp2 units; P <= 2^8)
    const bool trig = tm > mrow + 8.f;
    if (__any(trig)) {
      const float al = trig ? __builtin_amdgcn_exp2f(mrow - tm) : 1.f;
      if (trig) mrow = tm;
      lsum *= al;
#pragma unroll
      for (int f = 0; f < 2; ++f)
#pragma unroll
        for (int i = 0; i < 16; ++i) o[f][i] *= al;
    }

    float rs = 0.f;
#pragma unroll
    for (int f = 0; f < 2; ++f)
#pragma unroll
      for (int i = 0; i < 16; ++i) {
        const float p = __builtin_amdgcn_exp2f(st[f][i] - mrow);
        st[f][i] = p;
        rs += p;
      }
    rs += __shfl_xor(rs, 32, 64);
    lsum += rs;

    // O^T += V^T P^T. pb for slice (f,s): elements e = st[f] regs 8s+e
    // (in-lane; lsV's sigma key layout matches exactly).
    __builtin_amdgcn_s_setprio(1);
#pragma unroll
    for (int f = 0; f < 2; ++f) {
      u32 pk[8];
#pragma unroll
      for (int i = 0; i < 8; ++i) {
        const u32 lo = bfc(st[f][2 * i]), hi = bfc(st[f][2 * i + 1]);
        pk[i] = lo | (hi << 16);
      }
#pragma unroll
      for (int s = 0; s < 2; ++s) {
        u32x4 pw;
        pw[0] = pk[4 * s + 0]; pw[1] = pk[4 * s + 1];
        pw[2] = pk[4 * s + 2]; pw[3] = pk[4 * s + 3];
        const bf16x8 pb = __builtin_bit_cast(bf16x8, pw);
        const int ks = f * 2 + s;
#pragma unroll
        for (int df2 = 0; df2 < 2; ++df2) {
          const bf16x8 vt = *reinterpret_cast<const bf16x8*>(
              &lsV[cur][df2 * 32 + l31][ks * 16 + h8]);
          o[df2] = __builtin_amdgcn_mfma_f32_32x32x16_bf16(vt, pb, o[df2], 0, 0, 0);
        }
      }
    }
    __builtin_amdgcn_s_setprio(0);

    // write next tile into the other buffer; single barrier per tile
    *reinterpret_cast<short8*>(&lsK[cur ^ 1][srow][scol]) = rk0;
    *reinterpret_cast<short8*>(&lsK[cur ^ 1][32 + srow][scol]) = rk1;
    *reinterpret_cast<ushort4*>(&lsV[cur ^ 1][srow][scol]) = rv0a;
    *reinterpret_cast<ushort4*>(&lsV[cur ^ 1][srow][scol + 4]) = rv0b;
    *reinterpret_cast<ushort4*>(&lsV[cur ^ 1][32 + srow][scol]) = rv1a;
    *reinterpret_cast<ushort4*>(&lsV[cur ^ 1][32 + srow][scol + 4]) = rv1b;
    __syncthreads();
    cur ^= 1;
  }

  // epilogue: O[q][d], q = l31, d = df2*32 + 8*rg + 4h + jj
  const float inv = 1.f / lsum;
#pragma unroll
  for (int df2 = 0; df2 < 2; ++df2)
#pragma unroll
    for (int rg = 0; rg < 4; ++rg) {
      ushort4 s4;
      s4.x = bfc(o[df2][rg * 4 + 0] * inv);
      s4.y = bfc(o[df2][rg * 4 + 1] * inv);
      s4.z = bfc(o[df2][rg * 4 + 2] * inv);
      s4.w = bfc(o[df2][rg * 4 + 3] * inv);
      *reinterpret_cast<ushort4*>(
          &O[(rowQ + l31) * 1024 + hc + df2 * 32 + rg * 8 + h * 4]) = s4;
    }
}

extern "C" void kernel_launch(void* const* d_in, const int* in_sizes, int n_in,
                              void* d_out, int out_size, void* d_ws, size_t ws_size,
                              hipStream_t stream) {
  const float* x_q = (const float*)d_in[0];
  const float* x_k = (const float*)d_in[1];
  const float* x_v = (const float*)d_in[2];
  const int*   msk = (const int*)d_in[3];
  const float* Wq  = (const float*)d_in[4];
  const float* bq  = (const float*)d_in[5];
  const float* Wk  = (const float*)d_in[6];
  const float* bk  = (const float*)d_in[7];
  const float* Wv  = (const float*)d_in[8];
  const float* bv  = (const float*)d_in[9];
  const float* Wo  = (const float*)d_in[10];
  const float* bo  = (const float*)d_in[11];

  const size_t NTOK = 4096, H = 1024;
  u16* xbf  = (u16*)d_ws;            // 3 * 4096*1024 bf16
  u16* wt   = xbf + 3 * NTOK * H;    // 4 * 1024*1024 bf16 (transposed weights)
  u16* qkv  = wt  + 4 * H * H;       // Q,K row-major; V slot holds Vt (transposed)
  u16* aout = qkv + 3 * NTOK * H;    // 4096*1024 bf16
  float* mb = (float*)(aout + NTOK * H);  // 4096 floats
  u16* vtb  = qkv + 2 * NTOK * H;    // Vt[b*1024 + c][s] (reuses V slot)

  k_cvt<<<dim3(4096), dim3(256), 0, stream>>>(x_q, xbf,              1048576);
  k_cvt<<<dim3(4096), dim3(256), 0, stream>>>(x_k, xbf + NTOK * H,   1048576);
  k_cvt<<<dim3(4096), dim3(256), 0, stream>>>(x_v, xbf + 2 * NTOK * H, 1048576);
  k_maskbias<<<dim3(16), dim3(256), 0, stream>>>(msk, mb, 4096);
  k_transcvt<<<dim3(32, 32), dim3(32, 8), 0, stream>>>(Wq, wt);
  k_transcvt<<<dim3(32, 32), dim3(32, 8), 0, stream>>>(Wk, wt + H * H);
  k_transcvt<<<dim3(32, 32), dim3(32, 8), 0, stream>>>(Wv, wt + 2 * H * H);
  k_transcvt<<<dim3(32, 32), dim3(32, 8), 0, stream>>>(Wo, wt + 3 * H * H);

  // Q,K,V = x{q,k,v} @ W{q,k,v} + b{q,k,v}; Q scaled by 0.125*log2(e) for exp2 softmax
  // z==2 (V) writes transposed into vtb.
  const float qscale = 0.125f * 1.4426950408889634f;
  k_gemm_bt<u16><<<dim3(32, 8, 3), dim3(256), 0, stream>>>(
      xbf, (long)(NTOK * H), wt, (long)(H * H), bq, bk, bv,
      qscale, 1.f, 1.f,
      qkv, (long)(NTOK * H), vtb, 4096, 1024, 1024);

  // attention (flat grid, XCD-grouped mapping inside)
  k_attn<<<dim3(512), dim3(256), 0, stream>>>(
      qkv, qkv + NTOK * H, vtb, mb, aout);

  // out = attn_out @ Wo + bo  (fp32 output)
  k_gemm_bt<float><<<dim3(32, 8, 1), dim3(256), 0, stream>>>(
      aout, 0L, wt + 3 * H * H, 0L, bo, bo, bo,
      1.f, 1.f, 1.f,
      (float*)d_out, 0L, nullptr, 4096, 1024, 1024);
}

// Round 8
// 149.167 us; speedup vs baseline: 1.1181x; 1.0691x over previous
//
#include <hip/hip_runtime.h>

#define DEVI static __device__ __forceinline__

typedef unsigned short u16;
typedef unsigned int u32;
typedef __attribute__((ext_vector_type(8))) __bf16 bf16x8;
typedef __attribute__((ext_vector_type(8))) short short8;
typedef __attribute__((ext_vector_type(4))) float f32x4;
typedef __attribute__((ext_vector_type(16))) float f32x16;
typedef __attribute__((ext_vector_type(4))) u32 u32x4;

DEVI u16 f2bf(float f) {
  union { float f; u32 u; } v; v.f = f;
  u32 r = v.u + 0x7fffu + ((v.u >> 16) & 1u);  // RNE
  return (u16)(r >> 16);
}

DEVI u16 bfc(float f) {
  union { __bf16 b; u16 u; } v; v.b = (__bf16)f; return v.u;
}

DEVI void gload16(const void* g, void* l) {
  __builtin_amdgcn_global_load_lds(
      (const __attribute__((address_space(1))) void*)g,
      (__attribute__((address_space(3))) void*)l,
      16, 0, 0);
}

// ---------------- fp32 -> bf16 convert (3 tensors, one launch) ----------------
__global__ void k_cvt3(const float* __restrict__ a, const float* __restrict__ b2,
                       const float* __restrict__ c, u16* __restrict__ out, int n4) {
  const int z = blockIdx.y;
  const float* in = (z == 0) ? a : ((z == 1) ? b2 : c);
  u16* o = out + (size_t)z * (size_t)n4 * 4;
  const int i = blockIdx.x * blockDim.x + threadIdx.x;
  if (i >= n4) return;
  const float4 v = reinterpret_cast<const float4*>(in)[i];
  ushort4 s;
  s.x = f2bf(v.x); s.y = f2bf(v.y); s.z = f2bf(v.z); s.w = f2bf(v.w);
  reinterpret_cast<ushort4*>(o)[i] = s;
}

// ---------------- mask -> additive float bias ----------------
__global__ void k_maskbias(const int* __restrict__ m, float* __restrict__ bias, int n) {
  int i = blockIdx.x * blockDim.x + threadIdx.x;
  if (i < n) bias[i] = (m[i] == 1) ? 0.f : -1e30f;
}

// ---------------- 4x W[k][n] fp32 -> Wt[n][k] bf16 (1024x1024), one launch ----
__global__ void k_transcvt4(const float* __restrict__ W0, const float* __restrict__ W1,
                            const float* __restrict__ W2, const float* __restrict__ W3,
                            u16* __restrict__ Wtb) {
  const int z = blockIdx.z;
  const float* W = (z == 0) ? W0 : ((z == 1) ? W1 : ((z == 2) ? W2 : W3));
  u16* Wt = Wtb + (size_t)z * 1024 * 1024;
  __shared__ float tl[32][33];
  const int n0 = blockIdx.x * 32, k0 = blockIdx.y * 32;
  const int tx = threadIdx.x, ty = threadIdx.y;
#pragma unroll
  for (int r = ty; r < 32; r += 8)
    tl[r][tx] = W[(size_t)(k0 + r) * 1024 + n0 + tx];
  __syncthreads();
#pragma unroll
  for (int r = ty; r < 32; r += 8)
    Wt[(size_t)(n0 + r) * 1024 + k0 + tx] = f2bf(tl[tx][r]);
}

// ---------------- GEMM: C[M][N] = (A[M][K](bf16) * Bt[N][K](bf16) + bias) * scale ----
DEVI void store1(u16* C, size_t i, float v) { C[i] = f2bf(v); }
DEVI void store1(float* C, size_t i, float v) { C[i] = v; }

template <typename OutT>
__global__ __launch_bounds__(256, 2) void k_gemm_bt(
    const u16* __restrict__ Abase, long aZ,
    const u16* __restrict__ Btbase, long bZ,
    const float* __restrict__ bias0, const float* __restrict__ bias1,
    const float* __restrict__ bias2,
    float s0, float s1, float s2,
    OutT* __restrict__ Cbase, long cZ, u16* __restrict__ Vt,
    int M, int N, int K) {
  const int z = blockIdx.z;
  const u16* A  = Abase  + (size_t)z * aZ;
  const u16* Bt = Btbase + (size_t)z * bZ;
  OutT* C = Cbase + (size_t)z * cZ;
  const float* bias = (z == 0) ? bias0 : ((z == 1) ? bias1 : bias2);
  const float scl = (z == 0) ? s0 : ((z == 1) ? s1 : s2);

  __shared__ u16 lsA[128 * 32];
  __shared__ u16 lsB[128 * 32];

  const int t = threadIdx.x;
  const int w = t >> 6, ln = t & 63;
  const int l15 = ln & 15, lhi = ln >> 4;
  const int wr = w >> 1, wc = w & 1;
  const int m0 = blockIdx.x * 128, n0 = blockIdx.y * 128;

  f32x4 acc[4][4] = {};

  for (int kt = 0; kt < K; kt += 32) {
#pragma unroll
    for (int i = 0; i < 2; ++i) {
      const int li = i * 256 + t;
      const int row = li >> 2, cb = (li & 3) << 3;
      gload16(A + (size_t)(m0 + row) * K + kt + cb,
              (char*)lsA + (i * 256 + w * 64) * 16);
      gload16(Bt + (size_t)(n0 + row) * K + kt + cb,
              (char*)lsB + (i * 256 + w * 64) * 16);
    }
    __syncthreads();

    bf16x8 af[4], bf_[4];
#pragma unroll
    for (int m = 0; m < 4; ++m)
      af[m] = *reinterpret_cast<const bf16x8*>(
          &lsA[(wr * 64 + m * 16 + l15) * 32 + lhi * 8]);
#pragma unroll
    for (int n = 0; n < 4; ++n)
      bf_[n] = *reinterpret_cast<const bf16x8*>(
          &lsB[(wc * 64 + n * 16 + l15) * 32 + lhi * 8]);
#pragma unroll
    for (int m = 0; m < 4; ++m)
#pragma unroll
      for (int n = 0; n < 4; ++n)
        acc[m][n] = __builtin_amdgcn_mfma_f32_16x16x32_bf16(af[m], bf_[n], acc[m][n], 0, 0, 0);
    __syncthreads();
  }

  if (Vt != nullptr && z == 2) {
    // transposed write: Vt[(b*1024 + c)][s], 4 consecutive tokens per quad
#pragma unroll
    for (int n = 0; n < 4; ++n) {
      const int c = n0 + wc * 64 + n * 16 + l15;
      const float bv = bias[c];
#pragma unroll
      for (int m = 0; m < 4; ++m) {
        const int r = m0 + wr * 64 + m * 16 + lhi * 4;
        ushort4 s4;
#pragma unroll
        for (int j = 0; j < 4; ++j) ((u16*)&s4)[j] = f2bf(acc[m][n][j] + bv);
        *reinterpret_cast<ushort4*>(
            &Vt[((size_t)((r >> 11) * 1024 + c)) * 2048 + (r & 2047)]) = s4;
      }
    }
    return;
  }

#pragma unroll
  for (int n = 0; n < 4; ++n) {
    const int c = n0 + wc * 64 + n * 16 + l15;
    const float bv = bias[c];
#pragma unroll
    for (int m = 0; m < 4; ++m)
#pragma unroll
      for (int j = 0; j < 4; ++j) {
        const int r = m0 + wr * 64 + m * 16 + lhi * 4 + j;
        store1(C, (size_t)r * N + c, (acc[m][n][j] + bv) * scl);
      }
  }
}

// ---------------- flash attention (32x32 MFMA, in-lane P, QK(t+1)||SM(t)) ------
// grid 512 flat, XCD-grouped. 4 waves/block, 32 q-rows/wave (q=lane&31). KVBLK=64.
// Software pipeline: QK^T(t+1) (MFMA, background) issues BEFORE SM(t) (VALU) so
// both pipes are busy within one wave. K LDS 3-deep (write lookahead +3),
// V LDS 2-deep (lookahead +2) -> ONE barrier/tile preserved:
//   slot lsK[t%3] written at iter t holds K(t+3); read at iter t+2 (barrier at
//   t+1 intervenes). lsV[t&1] read at iter t step PV, rewritten same iter after
//   the barrier; read again at t+2.
// P in-lane via sigma-staged lsV (verified R7). T13 defer-max.
__global__ __launch_bounds__(256, 2) void k_attn(
    const u16* __restrict__ Q, const u16* __restrict__ K, const u16* __restrict__ Vt,
    const float* __restrict__ MB, u16* __restrict__ O) {
  __shared__ u16 lsK[3][64][72];
  __shared__ u16 lsV[2][64][72];

  const int t = threadIdx.x, w = t >> 6, ln = t & 63;
  const int l31 = ln & 31, h = ln >> 5, h8 = h * 8;
  const int fid = blockIdx.x;                // 0..511
  const int xcd = fid & 7, slot = fid >> 3;  // 0..63
  const int pair = xcd * 4 + (slot >> 4);    // 0..31
  const int qt = slot & 15;
  const int hh = pair & 15, b = pair >> 4;

  const size_t rowQ = (size_t)b * 2048 + qt * 128 + w * 32;
  const int hc = hh * 64;

  const int srow = t >> 3, scol = (t & 7) << 3;
  const u16* Kg = K + ((size_t)b * 2048 + srow) * 1024 + hc + scol;
  const int half = t & 1;
  const int g16 = ((t & 7) >> 1) << 4;
  const u16* VgA = Vt + ((size_t)(b * 1024 + hc) + srow) * 2048 + g16 + 4 * half;
  const float* MBb = MB + b * 2048;

  bf16x8 qb[4];
#pragma unroll
  for (int ks = 0; ks < 4; ++ks)
    qb[ks] = *reinterpret_cast<const bf16x8*>(
        &Q[(rowQ + l31) * 1024 + hc + ks * 16 + h8]);

  f32x16 o[2];
#pragma unroll
  for (int i = 0; i < 16; ++i) { o[0][i] = 0.f; o[1][i] = 0.f; }
  float mrow = -1e30f, lsum = 0.f;

  // prologue: stage K(0..2) and V(0..1)
#pragma unroll
  for (int p = 0; p < 3; ++p) {
    const short8 a = *reinterpret_cast<const short8*>(Kg + (size_t)(p * 64) * 1024);
    const short8 c = *reinterpret_cast<const short8*>(Kg + (size_t)(p * 64 + 32) * 1024);
    *reinterpret_cast<short8*>(&lsK[p][srow][scol]) = a;
    *reinterpret_cast<short8*>(&lsK[p][32 + srow][scol]) = c;
  }
#pragma unroll
  for (int p = 0; p < 2; ++p) {
    const ushort4 a = *reinterpret_cast<const ushort4*>(VgA + p * 64);
    const ushort4 b4 = *reinterpret_cast<const ushort4*>(VgA + p * 64 + 8);
    const ushort4 c = *reinterpret_cast<const ushort4*>(VgA + 32 * 2048 + p * 64);
    const ushort4 d = *reinterpret_cast<const ushort4*>(VgA + 32 * 2048 + p * 64 + 8);
    *reinterpret_cast<ushort4*>(&lsV[p][srow][scol]) = a;
    *reinterpret_cast<ushort4*>(&lsV[p][srow][scol + 4]) = b4;
    *reinterpret_cast<ushort4*>(&lsV[p][32 + srow][scol]) = c;
    *reinterpret_cast<ushort4*>(&lsV[p][32 + srow][scol + 4]) = d;
  }
  __syncthreads();

  // QK(0) -> stA
  f32x16 stA[2], stB[2];
#pragma unroll
  for (int i = 0; i < 16; ++i) { stA[0][i] = 0.f; stA[1][i] = 0.f; }
#pragma unroll
  for (int ks = 0; ks < 4; ++ks) {
    const bf16x8 kb0 = *reinterpret_cast<const bf16x8*>(&lsK[0][l31][ks * 16 + h8]);
    const bf16x8 kb1 = *reinterpret_cast<const bf16x8*>(&lsK[0][32 + l31][ks * 16 + h8]);
    stA[0] = __builtin_amdgcn_mfma_f32_32x32x16_bf16(kb0, qb[ks], stA[0], 0, 0, 0);
    stA[1] = __builtin_amdgcn_mfma_f32_32x32x16_bf16(kb1, qb[ks], stA[1], 0, 0, 0);
  }

#define ATTN_BODY(T, CUR, NXT, SW)                                                  \
  {                                                                                 \
    const int tK = ((T) + 3) & 31, tV = ((T) + 2) & 31;                             \
    const short8 rk0 = *reinterpret_cast<const short8*>(Kg + (size_t)(tK * 64) * 1024); \
    const short8 rk1 = *reinterpret_cast<const short8*>(Kg + (size_t)(tK * 64 + 32) * 1024); \
    const ushort4 rv0a = *reinterpret_cast<const ushort4*>(VgA + tV * 64);          \
    const ushort4 rv0b = *reinterpret_cast<const ushort4*>(VgA + tV * 64 + 8);      \
    const ushort4 rv1a = *reinterpret_cast<const ushort4*>(VgA + 32 * 2048 + tV * 64); \
    const ushort4 rv1b = *reinterpret_cast<const ushort4*>(VgA + 32 * 2048 + tV * 64 + 8); \
    const int sK = ((SW) == 2) ? 0 : (SW) + 1;                                      \
    _Pragma("unroll")                                                               \
    for (int i = 0; i < 16; ++i) { NXT[0][i] = 0.f; NXT[1][i] = 0.f; }              \
    __builtin_amdgcn_s_setprio(1);                                                  \
    _Pragma("unroll")                                                               \
    for (int ks = 0; ks < 4; ++ks) {                                                \
      const bf16x8 kb0 = *reinterpret_cast<const bf16x8*>(&lsK[sK][l31][ks * 16 + h8]); \
      const bf16x8 kb1 = *reinterpret_cast<const bf16x8*>(&lsK[sK][32 + l31][ks * 16 + h8]); \
      NXT[0] = __builtin_amdgcn_mfma_f32_32x32x16_bf16(kb0, qb[ks], NXT[0], 0, 0, 0); \
      NXT[1] = __builtin_amdgcn_mfma_f32_32x32x16_bf16(kb1, qb[ks], NXT[1], 0, 0, 0); \
    }                                                                               \
    __builtin_amdgcn_s_setprio(0);                                                  \
    _Pragma("unroll")                                                               \
    for (int f = 0; f < 2; ++f)                                                     \
      _Pragma("unroll")                                                             \
      for (int rg = 0; rg < 4; ++rg) {                                              \
        const f32x4 bv = *reinterpret_cast<const f32x4*>(                           \
            &MBb[(T) * 64 + f * 32 + rg * 8 + h * 4]);                              \
        _Pragma("unroll")                                                           \
        for (int jj = 0; jj < 4; ++jj) CUR[f][rg * 4 + jj] += bv[jj];               \
      }                                                                             \
    float tm = CUR[0][0];                                                           \
    _Pragma("unroll")                                                               \
    for (int f = 0; f < 2; ++f)                                                     \
      _Pragma("unroll")                                                             \
      for (int i = 0; i < 16; ++i) tm = fmaxf(tm, CUR[f][i]);                       \
    tm = fmaxf(tm, __shfl_xor(tm, 32, 64));                                         \
    const bool trig = tm > mrow + 8.f;                                              \
    if (__any(trig)) {                                                              \
      const float al = trig ? __builtin_amdgcn_exp2f(mrow - tm) : 1.f;              \
      if (trig) mrow = tm;                                                          \
      lsum *= al;                                                                   \
      _Pragma("unroll")                                                             \
      for (int f = 0; f < 2; ++f)                                                   \
        _Pragma("unroll")                                                           \
        for (int i = 0; i < 16; ++i) o[f][i] *= al;                                 \
    }                                                                               \
    float rs = 0.f;                                                                 \
    _Pragma("unroll")                                                               \
    for (int f = 0; f < 2; ++f)                                                     \
      _Pragma("unroll")                                                             \
      for (int i = 0; i < 16; ++i) {                                                \
        const float p = __builtin_amdgcn_exp2f(CUR[f][i] - mrow);                   \
        CUR[f][i] = p;                                                              \
        rs += p;                                                                    \
      }                                                                             \
    rs += __shfl_xor(rs, 32, 64);                                                   \
    lsum += rs;                                                                     \
    __builtin_amdgcn_s_setprio(1);                                                  \
    _Pragma("unroll")                                                               \
    for (int f = 0; f < 2; ++f) {                                                   \
      u32 pk[8];                                                                    \
      _Pragma("unroll")                                                             \
      for (int i = 0; i < 8; ++i)                                                   \
        pk[i] = (u32)bfc(CUR[f][2 * i]) | ((u32)bfc(CUR[f][2 * i + 1]) << 16);      \
      _Pragma("unroll")                                                             \
      for (int s = 0; s < 2; ++s) {                                                 \
        u32x4 pw;                                                                   \
        pw[0] = pk[4 * s + 0]; pw[1] = pk[4 * s + 1];                               \
        pw[2] = pk[4 * s + 2]; pw[3] = pk[4 * s + 3];                               \
        const bf16x8 pb = __builtin_bit_cast(bf16x8, pw);                           \
        const int ks = f * 2 + s;                                                   \
        _Pragma("unroll")                                                           \
        for (int df2 = 0; df2 < 2; ++df2) {                                         \
          const bf16x8 vt = *reinterpret_cast<const bf16x8*>(                       \
              &lsV[(T) & 1][df2 * 32 + l31][ks * 16 + h8]);                         \
          o[df2] = __builtin_amdgcn_mfma_f32_32x32x16_bf16(vt, pb, o[df2], 0, 0, 0); \
        }                                                                           \
      }                                                                             \
    }                                                                               \
    __builtin_amdgcn_s_setprio(0);                                                  \
    __syncthreads();                                                                \
    *reinterpret_cast<short8*>(&lsK[SW][srow][scol]) = rk0;                         \
    *reinterpret_cast<short8*>(&lsK[SW][32 + srow][scol]) = rk1;                    \
    *reinterpret_cast<ushort4*>(&lsV[(T) & 1][srow][scol]) = rv0a;                  \
    *reinterpret_cast<ushort4*>(&lsV[(T) & 1][srow][scol + 4]) = rv0b;              \
    *reinterpret_cast<ushort4*>(&lsV[(T) & 1][32 + srow][scol]) = rv1a;             \
    *reinterpret_cast<ushort4*>(&lsV[(T) & 1][32 + srow][scol + 4]) = rv1b;         \
  }

  int sw = 0;
  for (int t2 = 0; t2 < 32; t2 += 2) {
    ATTN_BODY(t2, stA, stB, sw);
    sw = (sw == 2) ? 0 : sw + 1;
    ATTN_BODY(t2 + 1, stB, stA, sw);
    sw = (sw == 2) ? 0 : sw + 1;
  }
#undef ATTN_BODY

  // epilogue: O[q][d], q = l31, d = df2*32 + 8*rg + 4h + jj
  const float inv = 1.f / lsum;
#pragma unroll
  for (int df2 = 0; df2 < 2; ++df2)
#pragma unroll
    for (int rg = 0; rg < 4; ++rg) {
      ushort4 s4;
      s4.x = bfc(o[df2][rg * 4 + 0] * inv);
      s4.y = bfc(o[df2][rg * 4 + 1] * inv);
      s4.z = bfc(o[df2][rg * 4 + 2] * inv);
      s4.w = bfc(o[df2][rg * 4 + 3] * inv);
      *reinterpret_cast<ushort4*>(
          &O[(rowQ + l31) * 1024 + hc + df2 * 32 + rg * 8 + h * 4]) = s4;
    }
}

extern "C" void kernel_launch(void* const* d_in, const int* in_sizes, int n_in,
                              void* d_out, int out_size, void* d_ws, size_t ws_size,
                              hipStream_t stream) {
  const float* x_q = (const float*)d_in[0];
  const float* x_k = (const float*)d_in[1];
  const float* x_v = (const float*)d_in[2];
  const int*   msk = (const int*)d_in[3];
  const float* Wq  = (const float*)d_in[4];
  const float* bq  = (const float*)d_in[5];
  const float* Wk  = (const float*)d_in[6];
  const float* bk  = (const float*)d_in[7];
  const float* Wv  = (const float*)d_in[8];
  const float* bv  = (const float*)d_in[9];
  const float* Wo  = (const float*)d_in[10];
  const float* bo  = (const float*)d_in[11];

  const size_t NTOK = 4096, H = 1024;
  u16* xbf  = (u16*)d_ws;            // 3 * 4096*1024 bf16
  u16* wt   = xbf + 3 * NTOK * H;    // 4 * 1024*1024 bf16 (transposed weights)
  u16* qkv  = wt  + 4 * H * H;       // Q,K row-major; V slot holds Vt (transposed)
  u16* aout = qkv + 3 * NTOK * H;    // 4096*1024 bf16
  float* mb = (float*)(aout + NTOK * H);  // 4096 floats
  u16* vtb  = qkv + 2 * NTOK * H;    // Vt[b*1024 + c][s] (reuses V slot)

  k_cvt3<<<dim3(4096, 3), dim3(256), 0, stream>>>(x_q, x_k, x_v, xbf, 1048576);
  k_maskbias<<<dim3(16), dim3(256), 0, stream>>>(msk, mb, 4096);
  k_transcvt4<<<dim3(32, 32, 4), dim3(32, 8), 0, stream>>>(Wq, Wk, Wv, Wo, wt);

  // Q,K,V = x{q,k,v} @ W{q,k,v} + b{q,k,v}; Q scaled by 0.125*log2(e) for exp2 softmax
  // z==2 (V) writes transposed into vtb.
  const float qscale = 0.125f * 1.4426950408889634f;
  k_gemm_bt<u16><<<dim3(32, 8, 3), dim3(256), 0, stream>>>(
      xbf, (long)(NTOK * H), wt, (long)(H * H), bq, bk, bv,
      qscale, 1.f, 1.f,
      qkv, (long)(NTOK * H), vtb, 4096, 1024, 1024);

  // attention (flat grid, XCD-grouped mapping inside)
  k_attn<<<dim3(512), dim3(256), 0, stream>>>(
      qkv, qkv + NTOK * H, vtb, mb, aout);

  // out = attn_out @ Wo + bo  (fp32 output)
  k_gemm_bt<float><<<dim3(32, 8, 1), dim3(256), 0, stream>>>(
      aout, 0L, wt + 3 * H * H, 0L, bo, bo, bo,
      1.f, 1.f, 1.f,
      (float*)d_out, 0L, nullptr, 4096, 1024, 1024);
}

// Round 9
// 137.117 us; speedup vs baseline: 1.2164x; 1.0879x over previous
//
#include <hip/hip_runtime.h>

#define DEVI static __device__ __forceinline__

typedef unsigned short u16;
typedef unsigned int u32;
typedef __attribute__((ext_vector_type(8))) __bf16 bf16x8;
typedef __attribute__((ext_vector_type(8))) short short8;
typedef __attribute__((ext_vector_type(4))) float f32x4;
typedef __attribute__((ext_vector_type(16))) float f32x16;
typedef __attribute__((ext_vector_type(4))) u32 u32x4;

DEVI u16 f2bf(float f) {
  union { float f; u32 u; } v; v.f = f;
  u32 r = v.u + 0x7fffu + ((v.u >> 16) & 1u);  // RNE
  return (u16)(r >> 16);
}

DEVI u16 bfc(float f) {
  union { __bf16 b; u16 u; } v; v.b = (__bf16)f; return v.u;
}

DEVI void gload16(const void* g, void* l) {
  __builtin_amdgcn_global_load_lds(
      (const __attribute__((address_space(1))) void*)g,
      (__attribute__((address_space(3))) void*)l,
      16, 0, 0);
}

// ---------------- mask -> additive float bias ----------------
__global__ void k_maskbias(const int* __restrict__ m, float* __restrict__ bias, int n) {
  int i = blockIdx.x * blockDim.x + threadIdx.x;
  if (i < n) bias[i] = (m[i] == 1) ? 0.f : -1e30f;
}

// ---------------- 4x W[k][n] fp32 -> Wt[n][k] bf16 (1024x1024), one launch ----
__global__ void k_transcvt4(const float* __restrict__ W0, const float* __restrict__ W1,
                            const float* __restrict__ W2, const float* __restrict__ W3,
                            u16* __restrict__ Wtb) {
  const int z = blockIdx.z;
  const float* W = (z == 0) ? W0 : ((z == 1) ? W1 : ((z == 2) ? W2 : W3));
  u16* Wt = Wtb + (size_t)z * 1024 * 1024;
  __shared__ float tl[32][33];
  const int n0 = blockIdx.x * 32, k0 = blockIdx.y * 32;
  const int tx = threadIdx.x, ty = threadIdx.y;
#pragma unroll
  for (int r = ty; r < 32; r += 8)
    tl[r][tx] = W[(size_t)(k0 + r) * 1024 + n0 + tx];
  __syncthreads();
#pragma unroll
  for (int r = ty; r < 32; r += 8)
    Wt[(size_t)(n0 + r) * 1024 + k0 + tx] = f2bf(tl[tx][r]);
}

// ---------------- GEMM: C[M][N] = (A * Bt^T + bias) * scale ----------------
// CVTA: A is fp32 (per-z pointer), converted to bf16 during reg-staged LDS write
// (fuses the x fp32->bf16 pass into the GEMM). Else A is bf16 via global_load_lds.
DEVI void store1(u16* C, size_t i, float v) { C[i] = f2bf(v); }
DEVI void store1(float* C, size_t i, float v) { C[i] = v; }

template <typename OutT, bool CVTA>
__global__ __launch_bounds__(256, 2) void k_gemm_bt(
    const u16* __restrict__ Ab, long aZ,
    const float* __restrict__ Af0, const float* __restrict__ Af1,
    const float* __restrict__ Af2,
    const u16* __restrict__ Btbase, long bZ,
    const float* __restrict__ bias0, const float* __restrict__ bias1,
    const float* __restrict__ bias2,
    float s0, float s1, float s2,
    OutT* __restrict__ Cbase, long cZ, u16* __restrict__ Vt,
    int M, int N, int K) {
  const int z = blockIdx.z;
  const u16* A  = Ab + (size_t)z * aZ;
  const float* Af = (z == 0) ? Af0 : ((z == 1) ? Af1 : Af2);
  const u16* Bt = Btbase + (size_t)z * bZ;
  OutT* C = Cbase + (size_t)z * cZ;
  const float* bias = (z == 0) ? bias0 : ((z == 1) ? bias1 : bias2);
  const float scl = (z == 0) ? s0 : ((z == 1) ? s1 : s2);

  __shared__ u16 lsA[128 * 32];
  __shared__ u16 lsB[128 * 32];

  const int t = threadIdx.x;
  const int w = t >> 6, ln = t & 63;
  const int l15 = ln & 15, lhi = ln >> 4;
  const int wr = w >> 1, wc = w & 1;
  const int m0 = blockIdx.x * 128, n0 = blockIdx.y * 128;

  f32x4 acc[4][4] = {};

  for (int kt = 0; kt < K; kt += 32) {
#pragma unroll
    for (int i = 0; i < 2; ++i) {
      const int li = i * 256 + t;
      const int row = li >> 2, cb = (li & 3) << 3;
      if constexpr (CVTA) {
        const float* ap = Af + (size_t)(m0 + row) * K + kt + cb;
        const float4 f0 = *reinterpret_cast<const float4*>(ap);
        const float4 f1 = *reinterpret_cast<const float4*>(ap + 4);
        union { u16 us[8]; short8 s8; } u;
        u.us[0] = bfc(f0.x); u.us[1] = bfc(f0.y); u.us[2] = bfc(f0.z); u.us[3] = bfc(f0.w);
        u.us[4] = bfc(f1.x); u.us[5] = bfc(f1.y); u.us[6] = bfc(f1.z); u.us[7] = bfc(f1.w);
        *reinterpret_cast<short8*>((char*)lsA + (size_t)li * 16) = u.s8;
      } else {
        gload16(A + (size_t)(m0 + row) * K + kt + cb,
                (char*)lsA + (i * 256 + w * 64) * 16);
      }
      gload16(Bt + (size_t)(n0 + row) * K + kt + cb,
              (char*)lsB + (i * 256 + w * 64) * 16);
    }
    __syncthreads();

    bf16x8 af[4], bf_[4];
#pragma unroll
    for (int m = 0; m < 4; ++m)
      af[m] = *reinterpret_cast<const bf16x8*>(
          &lsA[(wr * 64 + m * 16 + l15) * 32 + lhi * 8]);
#pragma unroll
    for (int n = 0; n < 4; ++n)
      bf_[n] = *reinterpret_cast<const bf16x8*>(
          &lsB[(wc * 64 + n * 16 + l15) * 32 + lhi * 8]);
#pragma unroll
    for (int m = 0; m < 4; ++m)
#pragma unroll
      for (int n = 0; n < 4; ++n)
        acc[m][n] = __builtin_amdgcn_mfma_f32_16x16x32_bf16(af[m], bf_[n], acc[m][n], 0, 0, 0);
    __syncthreads();
  }

  if (Vt != nullptr && z == 2) {
    // transposed write: Vt[(b*1024 + c)][s], 4 consecutive tokens per quad
#pragma unroll
    for (int n = 0; n < 4; ++n) {
      const int c = n0 + wc * 64 + n * 16 + l15;
      const float bv = bias[c];
#pragma unroll
      for (int m = 0; m < 4; ++m) {
        const int r = m0 + wr * 64 + m * 16 + lhi * 4;
        ushort4 s4;
#pragma unroll
        for (int j = 0; j < 4; ++j) ((u16*)&s4)[j] = f2bf(acc[m][n][j] + bv);
        *reinterpret_cast<ushort4*>(
            &Vt[((size_t)((r >> 11) * 1024 + c)) * 2048 + (r & 2047)]) = s4;
      }
    }
    return;
  }

#pragma unroll
  for (int n = 0; n < 4; ++n) {
    const int c = n0 + wc * 64 + n * 16 + l15;
    const float bv = bias[c];
#pragma unroll
    for (int m = 0; m < 4; ++m)
#pragma unroll
      for (int j = 0; j < 4; ++j) {
        const int r = m0 + wr * 64 + m * 16 + lhi * 4 + j;
        store1(C, (size_t)r * N + c, (acc[m][n][j] + bv) * scl);
      }
  }
}

// ---------------- flash attention (32x32 MFMA, in-lane P, QK(t+1)||SM(t)) ------
// grid 512 flat, XCD-grouped. 4 waves/block, 32 q-rows/wave (q=lane&31). KVBLK=64.
// Pipeline: QK^T(t+1) (MFMA) issues BEFORE SM(t) (VALU). K LDS 3-deep (write
// lookahead +3), V 2-deep (+2), ONE barrier/tile (ledger verified R8).
// Mask bias pre-loads INITIALIZE the QK accumulator (no post-MFMA bias pass;
// MFMA accumulates onto {0,-1e30}; -1e30 absorbs, exp2 -> 0).
// P in-lane via sigma-staged lsV. T13 defer-max.
__global__ __launch_bounds__(256, 2) void k_attn(
    const u16* __restrict__ Q, const u16* __restrict__ K, const u16* __restrict__ Vt,
    const float* __restrict__ MB, u16* __restrict__ O) {
  __shared__ u16 lsK[3][64][72];
  __shared__ u16 lsV[2][64][72];

  const int t = threadIdx.x, w = t >> 6, ln = t & 63;
  const int l31 = ln & 31, h = ln >> 5, h8 = h * 8;
  const int fid = blockIdx.x;                // 0..511
  const int xcd = fid & 7, slot = fid >> 3;  // 0..63
  const int pair = xcd * 4 + (slot >> 4);    // 0..31
  const int qt = slot & 15;
  const int hh = pair & 15, b = pair >> 4;

  const size_t rowQ = (size_t)b * 2048 + qt * 128 + w * 32;
  const int hc = hh * 64;

  const int srow = t >> 3, scol = (t & 7) << 3;
  const u16* Kg = K + ((size_t)b * 2048 + srow) * 1024 + hc + scol;
  const int half = t & 1;
  const int g16 = ((t & 7) >> 1) << 4;
  const u16* VgA = Vt + ((size_t)(b * 1024 + hc) + srow) * 2048 + g16 + 4 * half;
  const float* MBb = MB + b * 2048;

  bf16x8 qb[4];
#pragma unroll
  for (int ks = 0; ks < 4; ++ks)
    qb[ks] = *reinterpret_cast<const bf16x8*>(
        &Q[(rowQ + l31) * 1024 + hc + ks * 16 + h8]);

  f32x16 o[2];
#pragma unroll
  for (int i = 0; i < 16; ++i) { o[0][i] = 0.f; o[1][i] = 0.f; }
  float mrow = -1e30f, lsum = 0.f;

  // prologue: stage K(0..2) and V(0..1)
#pragma unroll
  for (int p = 0; p < 3; ++p) {
    const short8 a = *reinterpret_cast<const short8*>(Kg + (size_t)(p * 64) * 1024);
    const short8 c = *reinterpret_cast<const short8*>(Kg + (size_t)(p * 64 + 32) * 1024);
    *reinterpret_cast<short8*>(&lsK[p][srow][scol]) = a;
    *reinterpret_cast<short8*>(&lsK[p][32 + srow][scol]) = c;
  }
#pragma unroll
  for (int p = 0; p < 2; ++p) {
    const ushort4 a = *reinterpret_cast<const ushort4*>(VgA + p * 64);
    const ushort4 b4 = *reinterpret_cast<const ushort4*>(VgA + p * 64 + 8);
    const ushort4 c = *reinterpret_cast<const ushort4*>(VgA + 32 * 2048 + p * 64);
    const ushort4 d = *reinterpret_cast<const ushort4*>(VgA + 32 * 2048 + p * 64 + 8);
    *reinterpret_cast<ushort4*>(&lsV[p][srow][scol]) = a;
    *reinterpret_cast<ushort4*>(&lsV[p][srow][scol + 4]) = b4;
    *reinterpret_cast<ushort4*>(&lsV[p][32 + srow][scol]) = c;
    *reinterpret_cast<ushort4*>(&lsV[p][32 + srow][scol + 4]) = d;
  }
  __syncthreads();

  // QK(0) -> stA (bias-initialized accumulator)
  f32x16 stA[2], stB[2];
#pragma unroll
  for (int f = 0; f < 2; ++f)
#pragma unroll
    for (int rg = 0; rg < 4; ++rg) {
      const f32x4 bv = *reinterpret_cast<const f32x4*>(&MBb[f * 32 + rg * 8 + h * 4]);
#pragma unroll
      for (int jj = 0; jj < 4; ++jj) stA[f][rg * 4 + jj] = bv[jj];
    }
#pragma unroll
  for (int ks = 0; ks < 4; ++ks) {
    const bf16x8 kb0 = *reinterpret_cast<const bf16x8*>(&lsK[0][l31][ks * 16 + h8]);
    const bf16x8 kb1 = *reinterpret_cast<const bf16x8*>(&lsK[0][32 + l31][ks * 16 + h8]);
    stA[0] = __builtin_amdgcn_mfma_f32_32x32x16_bf16(kb0, qb[ks], stA[0], 0, 0, 0);
    stA[1] = __builtin_amdgcn_mfma_f32_32x32x16_bf16(kb1, qb[ks], stA[1], 0, 0, 0);
  }

#define ATTN_BODY(T, CUR, NXT, SW)                                                  \
  {                                                                                 \
    const int tK = ((T) + 3) & 31, tV = ((T) + 2) & 31, tB = ((T) + 1) & 31;        \
    const short8 rk0 = *reinterpret_cast<const short8*>(Kg + (size_t)(tK * 64) * 1024); \
    const short8 rk1 = *reinterpret_cast<const short8*>(Kg + (size_t)(tK * 64 + 32) * 1024); \
    const ushort4 rv0a = *reinterpret_cast<const ushort4*>(VgA + tV * 64);          \
    const ushort4 rv0b = *reinterpret_cast<const ushort4*>(VgA + tV * 64 + 8);      \
    const ushort4 rv1a = *reinterpret_cast<const ushort4*>(VgA + 32 * 2048 + tV * 64); \
    const ushort4 rv1b = *reinterpret_cast<const ushort4*>(VgA + 32 * 2048 + tV * 64 + 8); \
    const int sK = ((SW) == 2) ? 0 : (SW) + 1;                                      \
    _Pragma("unroll")                                                               \
    for (int f = 0; f < 2; ++f)                                                     \
      _Pragma("unroll")                                                             \
      for (int rg = 0; rg < 4; ++rg) {                                              \
        const f32x4 bv = *reinterpret_cast<const f32x4*>(                           \
            &MBb[tB * 64 + f * 32 + rg * 8 + h * 4]);                               \
        _Pragma("unroll")                                                           \
        for (int jj = 0; jj < 4; ++jj) NXT[f][rg * 4 + jj] = bv[jj];                \
      }                                                                             \
    __builtin_amdgcn_s_setprio(1);                                                  \
    _Pragma("unroll")                                                               \
    for (int ks = 0; ks < 4; ++ks) {                                                \
      const bf16x8 kb0 = *reinterpret_cast<const bf16x8*>(&lsK[sK][l31][ks * 16 + h8]); \
      const bf16x8 kb1 = *reinterpret_cast<const bf16x8*>(&lsK[sK][32 + l31][ks * 16 + h8]); \
      NXT[0] = __builtin_amdgcn_mfma_f32_32x32x16_bf16(kb0, qb[ks], NXT[0], 0, 0, 0); \
      NXT[1] = __builtin_amdgcn_mfma_f32_32x32x16_bf16(kb1, qb[ks], NXT[1], 0, 0, 0); \
    }                                                                               \
    __builtin_amdgcn_s_setprio(0);                                                  \
    float tm = CUR[0][0];                                                           \
    _Pragma("unroll")                                                               \
    for (int f = 0; f < 2; ++f)                                                     \
      _Pragma("unroll")                                                             \
      for (int i = 0; i < 16; ++i) tm = fmaxf(tm, CUR[f][i]);                       \
    tm = fmaxf(tm, __shfl_xor(tm, 32, 64));                                         \
    const bool trig = tm > mrow + 8.f;                                              \
    if (__any(trig)) {                                                              \
      const float al = trig ? __builtin_amdgcn_exp2f(mrow - tm) : 1.f;              \
      if (trig) mrow = tm;                                                          \
      lsum *= al;                                                                   \
      _Pragma("unroll")                                                             \
      for (int f = 0; f < 2; ++f)                                                   \
        _Pragma("unroll")                                                           \
        for (int i = 0; i < 16; ++i) o[f][i] *= al;                                 \
    }                                                                               \
    float rs = 0.f;                                                                 \
    _Pragma("unroll")                                                               \
    for (int f = 0; f < 2; ++f)                                                     \
      _Pragma("unroll")                                                             \
      for (int i = 0; i < 16; ++i) {                                                \
        const float p = __builtin_amdgcn_exp2f(CUR[f][i] - mrow);                   \
        CUR[f][i] = p;                                                              \
        rs += p;                                                                    \
      }                                                                             \
    rs += __shfl_xor(rs, 32, 64);                                                   \
    lsum += rs;                                                                     \
    __builtin_amdgcn_s_setprio(1);                                                  \
    _Pragma("unroll")                                                               \
    for (int f = 0; f < 2; ++f) {                                                   \
      u32 pk[8];                                                                    \
      _Pragma("unroll")                                                             \
      for (int i = 0; i < 8; ++i)                                                   \
        pk[i] = (u32)bfc(CUR[f][2 * i]) | ((u32)bfc(CUR[f][2 * i + 1]) << 16);      \
      _Pragma("unroll")                                                             \
      for (int s = 0; s < 2; ++s) {                                                 \
        u32x4 pw;                                                                   \
        pw[0] = pk[4 * s + 0]; pw[1] = pk[4 * s + 1];                               \
        pw[2] = pk[4 * s + 2]; pw[3] = pk[4 * s + 3];                               \
        const bf16x8 pb = __builtin_bit_cast(bf16x8, pw);                           \
        const int ks = f * 2 + s;                                                   \
        _Pragma("unroll")                                                           \
        for (int df2 = 0; df2 < 2; ++df2) {                                         \
          const bf16x8 vt = *reinterpret_cast<const bf16x8*>(                       \
              &lsV[(T) & 1][df2 * 32 + l31][ks * 16 + h8]);                         \
          o[df2] = __builtin_amdgcn_mfma_f32_32x32x16_bf16(vt, pb, o[df2], 0, 0, 0); \
        }                                                                           \
      }                                                                             \
    }                                                                               \
    __builtin_amdgcn_s_setprio(0);                                                  \
    __syncthreads();                                                                \
    *reinterpret_cast<short8*>(&lsK[SW][srow][scol]) = rk0;                         \
    *reinterpret_cast<short8*>(&lsK[SW][32 + srow][scol]) = rk1;                    \
    *reinterpret_cast<ushort4*>(&lsV[(T) & 1][srow][scol]) = rv0a;                  \
    *reinterpret_cast<ushort4*>(&lsV[(T) & 1][srow][scol + 4]) = rv0b;              \
    *reinterpret_cast<ushort4*>(&lsV[(T) & 1][32 + srow][scol]) = rv1a;             \
    *reinterpret_cast<ushort4*>(&lsV[(T) & 1][32 + srow][scol + 4]) = rv1b;         \
  }

  int sw = 0;
  for (int t2 = 0; t2 < 32; t2 += 2) {
    ATTN_BODY(t2, stA, stB, sw);
    sw = (sw == 2) ? 0 : sw + 1;
    ATTN_BODY(t2 + 1, stB, stA, sw);
    sw = (sw == 2) ? 0 : sw + 1;
  }
#undef ATTN_BODY

  // epilogue: O[q][d], q = l31, d = df2*32 + 8*rg + 4h + jj
  const float inv = 1.f / lsum;
#pragma unroll
  for (int df2 = 0; df2 < 2; ++df2)
#pragma unroll
    for (int rg = 0; rg < 4; ++rg) {
      ushort4 s4;
      s4.x = bfc(o[df2][rg * 4 + 0] * inv);
      s4.y = bfc(o[df2][rg * 4 + 1] * inv);
      s4.z = bfc(o[df2][rg * 4 + 2] * inv);
      s4.w = bfc(o[df2][rg * 4 + 3] * inv);
      *reinterpret_cast<ushort4*>(
          &O[(rowQ + l31) * 1024 + hc + df2 * 32 + rg * 8 + h * 4]) = s4;
    }
}

extern "C" void kernel_launch(void* const* d_in, const int* in_sizes, int n_in,
                              void* d_out, int out_size, void* d_ws, size_t ws_size,
                              hipStream_t stream) {
  const float* x_q = (const float*)d_in[0];
  const float* x_k = (const float*)d_in[1];
  const float* x_v = (const float*)d_in[2];
  const int*   msk = (const int*)d_in[3];
  const float* Wq  = (const float*)d_in[4];
  const float* bq  = (const float*)d_in[5];
  const float* Wk  = (const float*)d_in[6];
  const float* bk  = (const float*)d_in[7];
  const float* Wv  = (const float*)d_in[8];
  const float* bv  = (const float*)d_in[9];
  const float* Wo  = (const float*)d_in[10];
  const float* bo  = (const float*)d_in[11];

  const size_t NTOK = 4096, H = 1024;
  u16* wt   = (u16*)d_ws;            // 4 * 1024*1024 bf16 (transposed weights)
  u16* qkv  = wt  + 4 * H * H;       // Q,K row-major; V slot holds Vt (transposed)
  u16* aout = qkv + 3 * NTOK * H;    // 4096*1024 bf16
  float* mb = (float*)(aout + NTOK * H);  // 4096 floats
  u16* vtb  = qkv + 2 * NTOK * H;    // Vt[b*1024 + c][s] (reuses V slot)

  k_maskbias<<<dim3(16), dim3(256), 0, stream>>>(msk, mb, 4096);
  k_transcvt4<<<dim3(32, 32, 4), dim3(32, 8), 0, stream>>>(Wq, Wk, Wv, Wo, wt);

  // Q,K,V = x{q,k,v} @ W{q,k,v} + b{q,k,v}; fp32 A converted in-staging.
  // Q scaled by 0.125*log2(e) for exp2 softmax; z==2 (V) writes transposed.
  const float qscale = 0.125f * 1.4426950408889634f;
  k_gemm_bt<u16, true><<<dim3(32, 8, 3), dim3(256), 0, stream>>>(
      nullptr, 0L, x_q, x_k, x_v, wt, (long)(H * H), bq, bk, bv,
      qscale, 1.f, 1.f,
      qkv, (long)(NTOK * H), vtb, 4096, 1024, 1024);

  // attention (flat grid, XCD-grouped mapping inside)
  k_attn<<<dim3(512), dim3(256), 0, stream>>>(
      qkv, qkv + NTOK * H, vtb, mb, aout);

  // out = attn_out @ Wo + bo  (fp32 output)
  k_gemm_bt<float, false><<<dim3(32, 8, 1), dim3(256), 0, stream>>>(
      aout, 0L, nullptr, nullptr, nullptr, wt + 3 * H * H, 0L, bo, bo, bo,
      1.f, 1.f, 1.f,
      (float*)d_out, 0L, nullptr, 4096, 1024, 1024);
}

// Round 10
// 130.280 us; speedup vs baseline: 1.2802x; 1.0525x over previous
//
#include <hip/hip_runtime.h>

#define DEVI static __device__ __forceinline__

typedef unsigned short u16;
typedef unsigned int u32;
typedef __attribute__((ext_vector_type(8))) __bf16 bf16x8;
typedef __attribute__((ext_vector_type(8))) short short8;
typedef __attribute__((ext_vector_type(4))) float f32x4;
typedef __attribute__((ext_vector_type(16))) float f32x16;
typedef __attribute__((ext_vector_type(4))) u32 u32x4;

DEVI u16 f2bf(float f) {
  union { float f; u32 u; } v; v.f = f;
  u32 r = v.u + 0x7fffu + ((v.u >> 16) & 1u);  // RNE
  return (u16)(r >> 16);
}

DEVI u16 bfc(float f) {
  union { __bf16 b; u16 u; } v; v.b = (__bf16)f; return v.u;
}

DEVI void gload16(const void* g, void* l) {
  __builtin_amdgcn_global_load_lds(
      (const __attribute__((address_space(1))) void*)g,
      (__attribute__((address_space(3))) void*)l,
      16, 0, 0);
}

// ---- 4x W[k][n] fp32 -> Wt[n][k] bf16 (z<4) + mask->bias (z==4), one launch ----
__global__ void k_prep(const float* __restrict__ W0, const float* __restrict__ W1,
                       const float* __restrict__ W2, const float* __restrict__ W3,
                       u16* __restrict__ Wtb,
                       const int* __restrict__ msk, float* __restrict__ bias) {
  const int z = blockIdx.z;
  if (z == 4) {
    if (blockIdx.x < 16 && blockIdx.y == 0) {
      const int tid = threadIdx.y * 32 + threadIdx.x;
      const int i = blockIdx.x * 256 + tid;
      bias[i] = (msk[i] == 1) ? 0.f : -1e30f;
    }
    return;
  }
  const float* W = (z == 0) ? W0 : ((z == 1) ? W1 : ((z == 2) ? W2 : W3));
  u16* Wt = Wtb + (size_t)z * 1024 * 1024;
  __shared__ float tl[32][33];
  const int n0 = blockIdx.x * 32, k0 = blockIdx.y * 32;
  const int tx = threadIdx.x, ty = threadIdx.y;
#pragma unroll
  for (int r = ty; r < 32; r += 8)
    tl[r][tx] = W[(size_t)(k0 + r) * 1024 + n0 + tx];
  __syncthreads();
#pragma unroll
  for (int r = ty; r < 32; r += 8)
    Wt[(size_t)(n0 + r) * 1024 + k0 + tx] = f2bf(tl[tx][r]);
}

// ---------------- GEMM: C[M][N] = (A * Bt^T + bias) * scale ----------------
// BM=128 fixed, BN in {128,64}. CVTA: A fp32, converted during reg-staged LDS
// write with a one-K-step register prefetch (hides the A-load latency).
DEVI void store1(u16* C, size_t i, float v) { C[i] = f2bf(v); }
DEVI void store1(float* C, size_t i, float v) { C[i] = v; }

template <typename OutT, bool CVTA, int BN>
__global__ __launch_bounds__(256, 2) void k_gemm_bt(
    const u16* __restrict__ Ab, long aZ,
    const float* __restrict__ Af0, const float* __restrict__ Af1,
    const float* __restrict__ Af2,
    const u16* __restrict__ Btbase, long bZ,
    const float* __restrict__ bias0, const float* __restrict__ bias1,
    const float* __restrict__ bias2,
    float s0, float s1, float s2,
    OutT* __restrict__ Cbase, long cZ, u16* __restrict__ Vt,
    int M, int N, int K) {
  const int z = blockIdx.z;
  const u16* A  = Ab + (size_t)z * aZ;
  const float* Af = (z == 0) ? Af0 : ((z == 1) ? Af1 : Af2);
  const u16* Bt = Btbase + (size_t)z * bZ;
  OutT* C = Cbase + (size_t)z * cZ;
  const float* bias = (z == 0) ? bias0 : ((z == 1) ? bias1 : bias2);
  const float scl = (z == 0) ? s0 : ((z == 1) ? s1 : s2);

  constexpr int NF = BN / 32;      // n-frags per wave
  __shared__ u16 lsA[128 * 32];
  __shared__ u16 lsB[BN * 32];

  const int t = threadIdx.x;
  const int w = t >> 6, ln = t & 63;
  const int l15 = ln & 15, lhi = ln >> 4;
  const int wr = w >> 1, wc = w & 1;
  const int m0 = blockIdx.x * 128, n0 = blockIdx.y * BN;

  f32x4 acc[4][NF] = {};

  float4 pA0[2], pA1[2];
  if constexpr (CVTA) {
#pragma unroll
    for (int i = 0; i < 2; ++i) {
      const int li = i * 256 + t;
      const int row = li >> 2, cb = (li & 3) << 3;
      const float* ap = Af + (size_t)(m0 + row) * K + cb;
      pA0[i] = *reinterpret_cast<const float4*>(ap);
      pA1[i] = *reinterpret_cast<const float4*>(ap + 4);
    }
  }

  for (int kt = 0; kt < K; kt += 32) {
    // A staging (128x32)
#pragma unroll
    for (int i = 0; i < 2; ++i) {
      const int li = i * 256 + t;
      const int row = li >> 2, cb = (li & 3) << 3;
      if constexpr (CVTA) {
        union { u16 us[8]; short8 s8; } u;
        u.us[0] = bfc(pA0[i].x); u.us[1] = bfc(pA0[i].y);
        u.us[2] = bfc(pA0[i].z); u.us[3] = bfc(pA0[i].w);
        u.us[4] = bfc(pA1[i].x); u.us[5] = bfc(pA1[i].y);
        u.us[6] = bfc(pA1[i].z); u.us[7] = bfc(pA1[i].w);
        *reinterpret_cast<short8*>((char*)lsA + (size_t)li * 16) = u.s8;
      } else {
        gload16(A + (size_t)(m0 + row) * K + kt + cb,
                (char*)lsA + (i * 256 + w * 64) * 16);
      }
    }
    // B staging (BNx32)
#pragma unroll
    for (int i = 0; i < BN / 64; ++i) {
      const int li = i * 256 + t;
      const int row = li >> 2, cb = (li & 3) << 3;
      gload16(Bt + (size_t)(n0 + row) * K + kt + cb,
              (char*)lsB + (i * 256 + w * 64) * 16);
    }
    // prefetch next A tile into regs (consumed next iteration)
    if constexpr (CVTA) {
      if (kt + 32 < K) {
#pragma unroll
        for (int i = 0; i < 2; ++i) {
          const int li = i * 256 + t;
          const int row = li >> 2, cb = (li & 3) << 3;
          const float* ap = Af + (size_t)(m0 + row) * K + kt + 32 + cb;
          pA0[i] = *reinterpret_cast<const float4*>(ap);
          pA1[i] = *reinterpret_cast<const float4*>(ap + 4);
        }
      }
    }
    __syncthreads();

    bf16x8 af[4], bf_[NF];
#pragma unroll
    for (int m = 0; m < 4; ++m)
      af[m] = *reinterpret_cast<const bf16x8*>(
          &lsA[(wr * 64 + m * 16 + l15) * 32 + lhi * 8]);
#pragma unroll
    for (int n = 0; n < NF; ++n)
      bf_[n] = *reinterpret_cast<const bf16x8*>(
          &lsB[(wc * (BN / 2) + n * 16 + l15) * 32 + lhi * 8]);
#pragma unroll
    for (int m = 0; m < 4; ++m)
#pragma unroll
      for (int n = 0; n < NF; ++n)
        acc[m][n] = __builtin_amdgcn_mfma_f32_16x16x32_bf16(af[m], bf_[n], acc[m][n], 0, 0, 0);
    __syncthreads();
  }

  if constexpr (BN == 128) {
    if (Vt != nullptr && z == 2) {
      // transposed write: Vt[(b*1024 + c)][s], 4 consecutive tokens per quad
#pragma unroll
      for (int n = 0; n < NF; ++n) {
        const int c = n0 + wc * 64 + n * 16 + l15;
        const float bv = bias[c];
#pragma unroll
        for (int m = 0; m < 4; ++m) {
          const int r = m0 + wr * 64 + m * 16 + lhi * 4;
          ushort4 s4;
#pragma unroll
          for (int j = 0; j < 4; ++j) ((u16*)&s4)[j] = f2bf(acc[m][n][j] + bv);
          *reinterpret_cast<ushort4*>(
              &Vt[((size_t)((r >> 11) * 1024 + c)) * 2048 + (r & 2047)]) = s4;
        }
      }
      return;
    }
  }

#pragma unroll
  for (int n = 0; n < NF; ++n) {
    const int c = n0 + wc * (BN / 2) + n * 16 + l15;
    const float bv = bias[c];
#pragma unroll
    for (int m = 0; m < 4; ++m)
#pragma unroll
      for (int j = 0; j < 4; ++j) {
        const int r = m0 + wr * 64 + m * 16 + lhi * 4 + j;
        store1(C, (size_t)r * N + c, (acc[m][n][j] + bv) * scl);
      }
  }
}

// ---------------- flash attention (32x32 MFMA, in-lane P, QK(t+1)||SM(t)) ------
// grid 512 flat, XCD-grouped. 4 waves/block, 32 q-rows/wave (q=lane&31). KVBLK=64.
// Pipeline: QK^T(t+1) (MFMA) issues BEFORE SM(t) (VALU). K LDS 3-deep (write
// lookahead +3), V 2-deep (+2), ONE barrier/tile. Mask bias pre-loads INITIALIZE
// the QK accumulator. P in-lane via sigma-staged lsV. T13 defer-max.
// lsum kept per-lane-partial; cross-half sum deferred to the epilogue.
__global__ __launch_bounds__(256, 2) void k_attn(
    const u16* __restrict__ Q, const u16* __restrict__ K, const u16* __restrict__ Vt,
    const float* __restrict__ MB, u16* __restrict__ O) {
  __shared__ u16 lsK[3][64][72];
  __shared__ u16 lsV[2][64][72];

  const int t = threadIdx.x, w = t >> 6, ln = t & 63;
  const int l31 = ln & 31, h = ln >> 5, h8 = h * 8;
  const int fid = blockIdx.x;                // 0..511
  const int xcd = fid & 7, slot = fid >> 3;  // 0..63
  const int pair = xcd * 4 + (slot >> 4);    // 0..31
  const int qt = slot & 15;
  const int hh = pair & 15, b = pair >> 4;

  const size_t rowQ = (size_t)b * 2048 + qt * 128 + w * 32;
  const int hc = hh * 64;

  const int srow = t >> 3, scol = (t & 7) << 3;
  const u16* Kg = K + ((size_t)b * 2048 + srow) * 1024 + hc + scol;
  const int half = t & 1;
  const int g16 = ((t & 7) >> 1) << 4;
  const u16* VgA = Vt + ((size_t)(b * 1024 + hc) + srow) * 2048 + g16 + 4 * half;
  const float* MBb = MB + b * 2048;

  bf16x8 qb[4];
#pragma unroll
  for (int ks = 0; ks < 4; ++ks)
    qb[ks] = *reinterpret_cast<const bf16x8*>(
        &Q[(rowQ + l31) * 1024 + hc + ks * 16 + h8]);

  f32x16 o[2];
#pragma unroll
  for (int i = 0; i < 16; ++i) { o[0][i] = 0.f; o[1][i] = 0.f; }
  float mrow = -1e30f, lsum = 0.f;

  // prologue: stage K(0..2) and V(0..1)
#pragma unroll
  for (int p = 0; p < 3; ++p) {
    const short8 a = *reinterpret_cast<const short8*>(Kg + (size_t)(p * 64) * 1024);
    const short8 c = *reinterpret_cast<const short8*>(Kg + (size_t)(p * 64 + 32) * 1024);
    *reinterpret_cast<short8*>(&lsK[p][srow][scol]) = a;
    *reinterpret_cast<short8*>(&lsK[p][32 + srow][scol]) = c;
  }
#pragma unroll
  for (int p = 0; p < 2; ++p) {
    const ushort4 a = *reinterpret_cast<const ushort4*>(VgA + p * 64);
    const ushort4 b4 = *reinterpret_cast<const ushort4*>(VgA + p * 64 + 8);
    const ushort4 c = *reinterpret_cast<const ushort4*>(VgA + 32 * 2048 + p * 64);
    const ushort4 d = *reinterpret_cast<const ushort4*>(VgA + 32 * 2048 + p * 64 + 8);
    *reinterpret_cast<ushort4*>(&lsV[p][srow][scol]) = a;
    *reinterpret_cast<ushort4*>(&lsV[p][srow][scol + 4]) = b4;
    *reinterpret_cast<ushort4*>(&lsV[p][32 + srow][scol]) = c;
    *reinterpret_cast<ushort4*>(&lsV[p][32 + srow][scol + 4]) = d;
  }
  __syncthreads();

  // QK(0) -> stA (bias-initialized accumulator)
  f32x16 stA[2], stB[2];
#pragma unroll
  for (int f = 0; f < 2; ++f)
#pragma unroll
    for (int rg = 0; rg < 4; ++rg) {
      const f32x4 bv = *reinterpret_cast<const f32x4*>(&MBb[f * 32 + rg * 8 + h * 4]);
#pragma unroll
      for (int jj = 0; jj < 4; ++jj) stA[f][rg * 4 + jj] = bv[jj];
    }
#pragma unroll
  for (int ks = 0; ks < 4; ++ks) {
    const bf16x8 kb0 = *reinterpret_cast<const bf16x8*>(&lsK[0][l31][ks * 16 + h8]);
    const bf16x8 kb1 = *reinterpret_cast<const bf16x8*>(&lsK[0][32 + l31][ks * 16 + h8]);
    stA[0] = __builtin_amdgcn_mfma_f32_32x32x16_bf16(kb0, qb[ks], stA[0], 0, 0, 0);
    stA[1] = __builtin_amdgcn_mfma_f32_32x32x16_bf16(kb1, qb[ks], stA[1], 0, 0, 0);
  }

#define ATTN_BODY(T, CUR, NXT, SW)                                                  \
  {                                                                                 \
    const int tK = ((T) + 3) & 31, tV = ((T) + 2) & 31, tB = ((T) + 1) & 31;        \
    const short8 rk0 = *reinterpret_cast<const short8*>(Kg + (size_t)(tK * 64) * 1024); \
    const short8 rk1 = *reinterpret_cast<const short8*>(Kg + (size_t)(tK * 64 + 32) * 1024); \
    const ushort4 rv0a = *reinterpret_cast<const ushort4*>(VgA + tV * 64);          \
    const ushort4 rv0b = *reinterpret_cast<const ushort4*>(VgA + tV * 64 + 8);      \
    const ushort4 rv1a = *reinterpret_cast<const ushort4*>(VgA + 32 * 2048 + tV * 64); \
    const ushort4 rv1b = *reinterpret_cast<const ushort4*>(VgA + 32 * 2048 + tV * 64 + 8); \
    const int sK = ((SW) == 2) ? 0 : (SW) + 1;                                      \
    _Pragma("unroll")                                                               \
    for (int f = 0; f < 2; ++f)                                                     \
      _Pragma("unroll")                                                             \
      for (int rg = 0; rg < 4; ++rg) {                                              \
        const f32x4 bv = *reinterpret_cast<const f32x4*>(                           \
            &MBb[tB * 64 + f * 32 + rg * 8 + h * 4]);                               \
        _Pragma("unroll")                                                           \
        for (int jj = 0; jj < 4; ++jj) NXT[f][rg * 4 + jj] = bv[jj];                \
      }                                                                             \
    __builtin_amdgcn_s_setprio(1);                                                  \
    _Pragma("unroll")                                                               \
    for (int ks = 0; ks < 4; ++ks) {                                                \
      const bf16x8 kb0 = *reinterpret_cast<const bf16x8*>(&lsK[sK][l31][ks * 16 + h8]); \
      const bf16x8 kb1 = *reinterpret_cast<const bf16x8*>(&lsK[sK][32 + l31][ks * 16 + h8]); \
      NXT[0] = __builtin_amdgcn_mfma_f32_32x32x16_bf16(kb0, qb[ks], NXT[0], 0, 0, 0); \
      NXT[1] = __builtin_amdgcn_mfma_f32_32x32x16_bf16(kb1, qb[ks], NXT[1], 0, 0, 0); \
    }                                                                               \
    __builtin_amdgcn_s_setprio(0);                                                  \
    float tm = CUR[0][0];                                                           \
    _Pragma("unroll")                                                               \
    for (int f = 0; f < 2; ++f)                                                     \
      _Pragma("unroll")                                                             \
      for (int i = 0; i < 16; ++i) tm = fmaxf(tm, CUR[f][i]);                       \
    tm = fmaxf(tm, __shfl_xor(tm, 32, 64));                                         \
    const bool trig = tm > mrow + 8.f;                                              \
    if (__any(trig)) {                                                              \
      const float al = trig ? __builtin_amdgcn_exp2f(mrow - tm) : 1.f;              \
      if (trig) mrow = tm;                                                          \
      lsum *= al;                                                                   \
      _Pragma("unroll")                                                             \
      for (int f = 0; f < 2; ++f)                                                   \
        _Pragma("unroll")                                                           \
        for (int i = 0; i < 16; ++i) o[f][i] *= al;                                 \
    }                                                                               \
    float rs = 0.f;                                                                 \
    _Pragma("unroll")                                                               \
    for (int f = 0; f < 2; ++f)                                                     \
      _Pragma("unroll")                                                             \
      for (int i = 0; i < 16; ++i) {                                                \
        const float p = __builtin_amdgcn_exp2f(CUR[f][i] - mrow);                   \
        CUR[f][i] = p;                                                              \
        rs += p;                                                                    \
      }                                                                             \
    lsum += rs;                                                                     \
    __builtin_amdgcn_s_setprio(1);                                                  \
    _Pragma("unroll")                                                               \
    for (int f = 0; f < 2; ++f) {                                                   \
      u32 pk[8];                                                                    \
      _Pragma("unroll")                                                             \
      for (int i = 0; i < 8; ++i)                                                   \
        pk[i] = (u32)bfc(CUR[f][2 * i]) | ((u32)bfc(CUR[f][2 * i + 1]) << 16);      \
      _Pragma("unroll")                                                             \
      for (int s = 0; s < 2; ++s) {                                                 \
        u32x4 pw;                                                                   \
        pw[0] = pk[4 * s + 0]; pw[1] = pk[4 * s + 1];                               \
        pw[2] = pk[4 * s + 2]; pw[3] = pk[4 * s + 3];                               \
        const bf16x8 pb = __builtin_bit_cast(bf16x8, pw);                           \
        const int ks = f * 2 + s;                                                   \
        _Pragma("unroll")                                                           \
        for (int df2 = 0; df2 < 2; ++df2) {                                         \
          const bf16x8 vt = *reinterpret_cast<const bf16x8*>(                       \
              &lsV[(T) & 1][df2 * 32 + l31][ks * 16 + h8]);                         \
          o[df2] = __builtin_amdgcn_mfma_f32_32x32x16_bf16(vt, pb, o[df2], 0, 0, 0); \
        }                                                                           \
      }                                                                             \
    }                                                                               \
    __builtin_amdgcn_s_setprio(0);                                                  \
    __syncthreads();                                                                \
    *reinterpret_cast<short8*>(&lsK[SW][srow][scol]) = rk0;                         \
    *reinterpret_cast<short8*>(&lsK[SW][32 + srow][scol]) = rk1;                    \
    *reinterpret_cast<ushort4*>(&lsV[(T) & 1][srow][scol]) = rv0a;                  \
    *reinterpret_cast<ushort4*>(&lsV[(T) & 1][srow][scol + 4]) = rv0b;              \
    *reinterpret_cast<ushort4*>(&lsV[(T) & 1][32 + srow][scol]) = rv1a;             \
    *reinterpret_cast<ushort4*>(&lsV[(T) & 1][32 + srow][scol + 4]) = rv1b;         \
  }

  int sw = 0;
  for (int t2 = 0; t2 < 32; t2 += 2) {
    ATTN_BODY(t2, stA, stB, sw);
    sw = (sw == 2) ? 0 : sw + 1;
    ATTN_BODY(t2 + 1, stB, stA, sw);
    sw = (sw == 2) ? 0 : sw + 1;
  }
#undef ATTN_BODY

  // epilogue: O[q][d], q = l31, d = df2*32 + 8*rg + 4h + jj
  const float ltot = lsum + __shfl_xor(lsum, 32, 64);
  const float inv = 1.f / ltot;
#pragma unroll
  for (int df2 = 0; df2 < 2; ++df2)
#pragma unroll
    for (int rg = 0; rg < 4; ++rg) {
      ushort4 s4;
      s4.x = bfc(o[df2][rg * 4 + 0] * inv);
      s4.y = bfc(o[df2][rg * 4 + 1] * inv);
      s4.z = bfc(o[df2][rg * 4 + 2] * inv);
      s4.w = bfc(o[df2][rg * 4 + 3] * inv);
      *reinterpret_cast<ushort4*>(
          &O[(rowQ + l31) * 1024 + hc + df2 * 32 + rg * 8 + h * 4]) = s4;
    }
}

extern "C" void kernel_launch(void* const* d_in, const int* in_sizes, int n_in,
                              void* d_out, int out_size, void* d_ws, size_t ws_size,
                              hipStream_t stream) {
  const float* x_q = (const float*)d_in[0];
  const float* x_k = (const float*)d_in[1];
  const float* x_v = (const float*)d_in[2];
  const int*   msk = (const int*)d_in[3];
  const float* Wq  = (const float*)d_in[4];
  const float* bq  = (const float*)d_in[5];
  const float* Wk  = (const float*)d_in[6];
  const float* bk  = (const float*)d_in[7];
  const float* Wv  = (const float*)d_in[8];
  const float* bv  = (const float*)d_in[9];
  const float* Wo  = (const float*)d_in[10];
  const float* bo  = (const float*)d_in[11];

  const size_t NTOK = 4096, H = 1024;
  u16* wt   = (u16*)d_ws;            // 4 * 1024*1024 bf16 (transposed weights)
  u16* qkv  = wt  + 4 * H * H;       // Q,K row-major; V slot holds Vt (transposed)
  u16* aout = qkv + 3 * NTOK * H;    // 4096*1024 bf16
  float* mb = (float*)(aout + NTOK * H);  // 4096 floats
  u16* vtb  = qkv + 2 * NTOK * H;    // Vt[b*1024 + c][s] (reuses V slot)

  k_prep<<<dim3(32, 32, 5), dim3(32, 8), 0, stream>>>(Wq, Wk, Wv, Wo, wt, msk, mb);

  // Q,K,V = x{q,k,v} @ W{q,k,v} + b{q,k,v}; fp32 A converted in-staging with
  // one-K-step register prefetch. Q scaled by 0.125*log2(e); z==2 writes Vt.
  const float qscale = 0.125f * 1.4426950408889634f;
  k_gemm_bt<u16, true, 128><<<dim3(32, 8, 3), dim3(256), 0, stream>>>(
      nullptr, 0L, x_q, x_k, x_v, wt, (long)(H * H), bq, bk, bv,
      qscale, 1.f, 1.f,
      qkv, (long)(NTOK * H), vtb, 4096, 1024, 1024);

  // attention (flat grid, XCD-grouped mapping inside)
  k_attn<<<dim3(512), dim3(256), 0, stream>>>(
      qkv, qkv + NTOK * H, vtb, mb, aout);

  // out = attn_out @ Wo + bo (fp32 output); BN=64 -> 512 blocks = 2/CU
  k_gemm_bt<float, false, 64><<<dim3(32, 16, 1), dim3(256), 0, stream>>>(
      aout, 0L, nullptr, nullptr, nullptr, wt + 3 * H * H, 0L, bo, bo, bo,
      1.f, 1.f, 1.f,
      (float*)d_out, 0L, nullptr, 4096, 1024, 1024);
}